// Round 9
// baseline (91895.911 us; speedup 1.0000x reference)
//
#include <hip/hip_runtime.h>
#include <cstdint>

#define LSEQ 256
#define BN_INV 0.99999500003750f

typedef float v4f __attribute__((ext_vector_type(4)));

#define DYN_L 133760   // 33440 floats: Xl 8320 | Tg 544 | W4 16384 | WX 2048/8192 | attn region

// LDS float offsets for the persistent kernel
#define L_XL   0
#define L_TG   8320
#define L_W4   8864      // 16384 floats: [Wih|Whh] image
#define L_WX   25248     // Wd (2048) | Wp1s (8192) | WFs (2048)
#define L_GS   27296     // 3968 (attn blocks only; after their 2048-float Wd)
#define L_AW   31264     // 288
#define L_PL   31552     // 256
#define L_DEC  31808     // 128
#define L_RED  31936     // 4
#define L_MISC 31944     // 2 ints (rank, R)  -> end < 33440

// per-XCD staging buffers (L2-resident; in h1's dead tail during k_loop)
#define XB_AC     0        // [2][16384]  att_c parity banks
#define XB_Z1     32768    // [2][16384]  z1 parity banks
#define XB_Z0     65536    // [16384]
#define XB_STRIDE 81920    // floats per XCD

struct Args {
  const float *enc_z, *ys;
  const int* ilens;
  const float *W_enc, *b_enc, *W_dec, *loc_kernel, *W_att, *g_w, *g_b;
  const float *Wp0, *bp0, *Wp1, *bp1;
  const float *Wih0, *Whh0, *bih0, *bhh0, *Wih1, *Whh1, *bih1, *bhh1;
  const float *Wf, *bf, *Wq, *bq;
  const float *pk0,*pb0,*bg0,*bb0,*pk1,*pb1,*bg1,*bb1,*pk2,*pb2,*bg2,*bb2;
  float *enc_proj, *pre_tmp, *pre_all, *G, *dec, *att_c;
  float *z0, *z1, *c0g, *c1g, *gpre0, *gpre1, *biasP0, *biasP1;
  float *before_t, *h0, *h1, *Wt0, *Wt1, *Wt2, *s0, *t0s, *s1, *t1s, *s2, *t2s;
  float *W0pack, *W1pack, *Wp1pack, *WFpack, *Wdpack, *xbuf;
  float *out_after, *out_before, *out_logits, *out_aws;
  unsigned *bars;   // [0..255] arrive flags, [384] go, [400..407] rk, [416..423] cnt
};

__device__ __forceinline__ float sigf(float x){ return 1.0f/(1.0f+expf(-x)); }
__device__ __forceinline__ float hsum(const v4f& v){ return v.x+v.y+v.z+v.w; }

// ---- coherent (device-scope, sc0 sc1) accessors: cross-XCD truth ----
__device__ __forceinline__ float cld(const float* p){
  return __hip_atomic_load(p, __ATOMIC_RELAXED, __HIP_MEMORY_SCOPE_AGENT);
}
__device__ __forceinline__ void cst(float* p, float v){
  __hip_atomic_store(p, v, __ATOMIC_RELAXED, __HIP_MEMORY_SCOPE_AGENT);
}
__device__ __forceinline__ v4f cld4(const float* p){
  v4f v;
  asm volatile("global_load_dwordx4 %0, %1, off sc0 sc1" : "=v"(v) : "v"(p));
  return v;
}
// ---- XCD-local (sc0: bypass L1, served by this XCD's L2) ----
__device__ __forceinline__ v4f l2ld4(const float* p){
  v4f v;
  asm volatile("global_load_dwordx4 %0, %1, off sc0" : "=v"(v) : "v"(p));
  return v;
}
#define CWAIT() do { asm volatile("s_waitcnt vmcnt(0)" ::: "memory"); \
                     __builtin_amdgcn_sched_barrier(0); } while(0)

// stage 32 rows x 256 floats (rowstride 512) into LDS (pitch 260) via LOADER
#define STAGE8(LOADER, base, koff, Xl) do{ \
  v4f r0,r1,r2,r3,r4,r5,r6,r7; \
  const float* _b = (base); const int _k = (koff); \
  { int f=tid;      r0=LOADER(_b + (size_t)(f>>6)*512 + _k + (f&63)*4); } \
  { int f=tid+256;  r1=LOADER(_b + (size_t)(f>>6)*512 + _k + (f&63)*4); } \
  { int f=tid+512;  r2=LOADER(_b + (size_t)(f>>6)*512 + _k + (f&63)*4); } \
  { int f=tid+768;  r3=LOADER(_b + (size_t)(f>>6)*512 + _k + (f&63)*4); } \
  { int f=tid+1024; r4=LOADER(_b + (size_t)(f>>6)*512 + _k + (f&63)*4); } \
  { int f=tid+1280; r5=LOADER(_b + (size_t)(f>>6)*512 + _k + (f&63)*4); } \
  { int f=tid+1536; r6=LOADER(_b + (size_t)(f>>6)*512 + _k + (f&63)*4); } \
  { int f=tid+1792; r7=LOADER(_b + (size_t)(f>>6)*512 + _k + (f&63)*4); } \
  CWAIT(); \
  __syncthreads(); \
  { int f=tid;      *(v4f*)&Xl[(f>>6)*260 + (f&63)*4] = r0; } \
  { int f=tid+256;  *(v4f*)&Xl[(f>>6)*260 + (f&63)*4] = r1; } \
  { int f=tid+512;  *(v4f*)&Xl[(f>>6)*260 + (f&63)*4] = r2; } \
  { int f=tid+768;  *(v4f*)&Xl[(f>>6)*260 + (f&63)*4] = r3; } \
  { int f=tid+1024; *(v4f*)&Xl[(f>>6)*260 + (f&63)*4] = r4; } \
  { int f=tid+1280; *(v4f*)&Xl[(f>>6)*260 + (f&63)*4] = r5; } \
  { int f=tid+1536; *(v4f*)&Xl[(f>>6)*260 + (f&63)*4] = r6; } \
  { int f=tid+1792; *(v4f*)&Xl[(f>>6)*260 + (f&63)*4] = r7; } \
  __syncthreads(); \
}while(0)

// ---------------- init: precomputes + per-block weight packs ----------------
__global__ void k_init(Args A){
  int tid0 = blockIdx.x*blockDim.x + threadIdx.x;
  int stride = gridDim.x*blockDim.x;
  for (int i = tid0; i < 512; i += stride) A.bars[i] = 0u;
  for (int i = tid0; i < 31*128; i += stride){
    int k = i >> 7, d = i & 127;
    float s = 0.f;
    for (int c = 0; c < 32; ++c) s += A.W_att[c*128+d]*A.loc_kernel[c*31+k];
    A.G[i] = s;
  }
  for (int i = tid0; i < 2048; i += stride){
    int u = i & 511, g = i >> 9;
    A.biasP0[u*4+g] = A.bih0[i]+A.bhh0[i];
    A.biasP1[u*4+g] = A.bih1[i]+A.bhh1[i];
  }
  for (int i = tid0; i < 16384; i += stride){ A.z0[i]=0.f; A.c0g[i]=0.f; A.c1g[i]=0.f; }
  for (int i = tid0; i < 32768; i += stride) A.z1[i]=0.f;
  for (int i = tid0; i < 65536; i += stride) A.gpre0[i]=0.f;
  for (int i = tid0; i < 4096; i += stride) A.dec[i]=0.f;
  for (int i = tid0; i < 512; i += stride){
    float s = A.bg0[i]*BN_INV; A.s0[i]=s; A.t0s[i]=s*A.pb0[i]+A.bb0[i];
    float u = A.bg1[i]*BN_INV; A.s1[i]=u; A.t1s[i]=u*A.pb1[i]+A.bb1[i];
  }
  for (int i = tid0; i < 80; i += stride){
    float s = A.bg2[i]*BN_INV; A.s2[i]=s; A.t2s[i]=s*A.pb2[i]+A.bb2[i];
  }
  for (int i = tid0; i < 5*80*512; i += stride){
    int k = i/(80*512); int r = i - k*(80*512); int c = r>>9, n = r&511;
    A.Wt0[i] = A.pk0[(n*80+c)*5+k];
  }
  for (int i = tid0; i < 5*512*512; i += stride){
    int k = i/(512*512); int r = i - k*(512*512); int c = r>>9, n = r&511;
    A.Wt1[i] = A.pk1[(n*512+c)*5+k];
  }
  for (int i = tid0; i < 5*512*80; i += stride){
    int k = i/(512*80); int r = i - k*(512*80); int c = r/80, n = r - c*80;
    A.Wt2[i] = A.pk2[(n*512+c)*5+k];
  }
  // ---- per-block weight packs (LDS image order => coalesced reload) ----
  for (int i = tid0; i < 128*16384; i += stride){
    int blk = i >> 14, idx = i & 16383;
    int kq = idx >> 6, rem = idx & 63, p = rem >> 2, kl = rem & 3;
    int k = kq*4 + kl;
    int gcol = (p & 3)*512 + blk*4 + (p >> 2);
    A.W0pack[i] = (k < 512) ? A.Wih0[(size_t)k*2048 + gcol]
                            : A.Whh0[(size_t)(k-512)*2048 + gcol];
  }
  for (int i = tid0; i < 128*16384; i += stride){
    int blk = i >> 14, idx = i & 16383;
    int kq = idx >> 6, rem = idx & 63, p = rem >> 2, kl = rem & 3;
    int k = kq*4 + kl;
    int gcol = (p & 3)*512 + blk*4 + (p >> 2);
    A.W1pack[i] = (k < 512) ? A.Wih1[(size_t)k*2048 + gcol]
                            : A.Whh1[(size_t)(k-512)*2048 + gcol];
  }
  for (int i = tid0; i < 64*8192; i += stride){
    int m = i >> 13, idx = i & 8191;
    int kq = idx >> 7, rem = idx & 127, p = rem >> 2, kl = rem & 3;
    int k = kq*4 + kl;
    int gcol = (p & 3)*512 + m*8 + (p >> 2);
    A.Wp1pack[i] = A.Wih0[(size_t)(512+k)*2048 + gcol];
  }
  for (int i = tid0; i < 41*2048; i += stride){
    int blk = i >> 11, k2 = i & 2047;
    int k = k2 >> 1, e = k2 & 1, c = blk*2 + e;
    A.WFpack[i] = (c < 80) ? A.Wf[(size_t)k*80 + c] : A.Wq[k];
  }
  for (int i = tid0; i < 32*2048; i += stride){
    int blk = i >> 11, j = i & 2047;
    int k = j >> 2, c = j & 3;
    A.Wdpack[i] = A.W_dec[(size_t)k*128 + blk*4 + c];
  }
}

// ---------------- enc_proj ----------------
__global__ void __launch_bounds__(256) k_encproj(Args A){
  __shared__ __align__(16) float As[32][128];
  int m0 = blockIdx.x*32;
  int tid = threadIdx.x;
  int d = tid & 127, half = tid >> 7;
  float acc[16];
  #pragma unroll
  for (int r = 0; r < 16; ++r) acc[r] = 0.f;
  for (int j0 = 0; j0 < 512; j0 += 128){
    for (int i = 0; i < 16; ++i){
      int e = tid + i*256; int r = e >> 7, j = e & 127;
      As[r][j] = A.enc_z[(size_t)(m0+r)*512 + j0 + j];
    }
    __syncthreads();
    for (int j = 0; j < 128; ++j){
      float w = A.W_enc[(size_t)(j0+j)*128 + d];
      #pragma unroll
      for (int r = 0; r < 16; ++r) acc[r] += As[half*16+r][j]*w;
    }
    __syncthreads();
  }
  float be = A.b_enc[d];
  for (int r = 0; r < 16; ++r)
    A.enc_proj[(size_t)(m0+half*16+r)*128 + d] = acc[r] + be;
}

// ---------------- prenet ----------------
__global__ void __launch_bounds__(256) k_pre0(Args A){
  __shared__ float As[32][80];
  int m0 = blockIdx.x*32, tid = threadIdx.x;
  for (int e = tid; e < 2560; e += 256){
    int r = e/80, o = e - r*80;
    int row = m0+r; int l = row & 255, b = row >> 8;
    As[r][o] = (l==0) ? 0.f : A.ys[((size_t)b*256 + (l-1))*80 + o];
  }
  __syncthreads();
  float acc[32];
  #pragma unroll
  for (int r = 0; r < 32; ++r) acc[r] = 0.f;
  for (int o = 0; o < 80; ++o){
    float w = A.Wp0[o*256 + tid];
    #pragma unroll
    for (int r = 0; r < 32; ++r) acc[r] += As[r][o]*w;
  }
  float bb = A.bp0[tid];
  for (int r = 0; r < 32; ++r){
    float v = acc[r]+bb;
    A.pre_tmp[(size_t)(m0+r)*256 + tid] = v>0.f?v:0.f;
  }
}

__global__ void __launch_bounds__(256) k_pre1(Args A){
  __shared__ float As[32][256];
  int m0 = blockIdx.x*32, tid = threadIdx.x;
  for (int e = tid; e < 8192; e += 256){
    int r = e >> 8, j = e & 255;
    As[r][j] = A.pre_tmp[(size_t)(m0+r)*256 + j];
  }
  __syncthreads();
  float acc[32];
  #pragma unroll
  for (int r = 0; r < 32; ++r) acc[r] = 0.f;
  for (int j = 0; j < 256; ++j){
    float w = A.Wp1[j*256 + tid];
    #pragma unroll
    for (int r = 0; r < 32; ++r) acc[r] += As[r][j]*w;
  }
  float bb = A.bp1[tid];
  for (int r = 0; r < 32; ++r){
    float v = acc[r]+bb;
    A.pre_all[(size_t)(m0+r)*256 + tid] = v>0.f?v:0.f;
  }
}

// ---- normal cached v4 load ----
__device__ __forceinline__ v4f nld4(const float* p){ return *(const v4f*)p; }

__device__ __forceinline__ void stage256x(const float* base, int koff, float* Xl, int tid){
  STAGE8(l2ld4, base, koff, Xl);
}

// ---- pre_all stager: rows at stride 65536 (batch-major), 256-wide rows ----
__device__ __forceinline__ void stage_pre(const float* base, float* Xl, int tid){
  v4f r0,r1,r2,r3,r4,r5,r6,r7;
  #define LDP(i,dst) { int f=tid+((i)<<8); int b=f>>6; int jq=f&63; \
      dst = *(const v4f*)(base + (size_t)b*65536 + jq*4); }
  LDP(0,r0) LDP(1,r1) LDP(2,r2) LDP(3,r3) LDP(4,r4) LDP(5,r5) LDP(6,r6) LDP(7,r7)
  #undef LDP
  __syncthreads();
  #define STP(i,src) { int f=tid+((i)<<8); int b=f>>6; int jq=f&63; \
      *(v4f*)&Xl[b*260 + jq*4] = src; }
  STP(0,r0) STP(1,r1) STP(2,r2) STP(3,r3) STP(4,r4) STP(5,r5) STP(6,r6) STP(7,r7)
  #undef STP
  __syncthreads();
}

// ---- per-XCD relay: cooperative sc1 slice-read -> sc0 write to XCD-local L2
// buffer -> generation-counter sync. All R blocks on this XCD participate.
__device__ __forceinline__ void relay(unsigned* ctr, const float* src, float* dst,
                                      int xcd, int rank, int R, unsigned ev, int tid){
  int lo4 = ((4096*rank)/R)*4, hi4 = ((4096*(rank+1))/R)*4;
  for (int i = lo4 + tid*4; i < hi4; i += 1024){
    v4f v = cld4(src + i);
    CWAIT();
    asm volatile("global_store_dwordx4 %0, %1, off sc0" :: "v"(dst + i), "v"(v));
  }
  __syncthreads();                       // drains the sc0 stores (vmcnt)
  if (tid == 0){
    __hip_atomic_fetch_add(&ctr[416+xcd], 1u, __ATOMIC_RELAXED, __HIP_MEMORY_SCOPE_AGENT);
    while (__hip_atomic_load(&ctr[416+xcd], __ATOMIC_RELAXED, __HIP_MEMORY_SCOPE_AGENT)
           < (unsigned)R*ev)
      __builtin_amdgcn_s_sleep(1);
  }
  __syncthreads();
}

// ---- K=256 chunk gemm ----
__device__ __forceinline__ void gemmK256(const float* __restrict__ W4,
                                         const float* __restrict__ Xl,
                                         int tid, v4f& a0, v4f& a1){
  const int q = tid & 7, b = tid >> 3;
  const float* xr = Xl + b*260;
  #pragma unroll 8
  for (int jq = 0; jq < 64; ++jq){
    v4f xv = *(const v4f*)&xr[jq*4];
    v4f w0 = *(const v4f*)&W4[jq*64 + q*4];
    v4f w1 = *(const v4f*)&W4[jq*64 + (q+8)*4];
    a0 += xv*w0; a1 += xv*w1;
  }
}

// ---- out(tt): 2 cols of [Wf|Wq], K=1024 over [z1; att_c] (from xcd L2 bufs) ----
__device__ __forceinline__ void out_phase(const Args& A, const float* z1b, const float* acb,
                                          int tt, int ob, int tid, float* Xl, float* Tg,
                                          const float* WF){
  int b = tid >> 3, sub = tid & 7;
  float acc0 = 0.f, acc1 = 0.f;
  for (int pass = 0; pass < 4; ++pass){
    const float* src = (pass < 2) ? z1b : acb;
    stage256x(src, (pass & 1)*256, Xl, tid);
    int kbase = pass*256;
    #pragma unroll 4
    for (int i = 0; i < 32; ++i){
      int k = sub + 8*i;
      float x = Xl[b*260 + k];
      acc0 += x*WF[(kbase+k)*2 + 0];
      acc1 += x*WF[(kbase+k)*2 + 1];
    }
    __syncthreads();
  }
  Tg[(b*8+sub)*2+0] = acc0; Tg[(b*8+sub)*2+1] = acc1;
  __syncthreads();
  if (tid < 64){
    int b2 = tid >> 1, e = tid & 1, cg = ob*2 + e;
    float v = (cg < 80) ? A.bf[cg] : A.bq[0];
    for (int s = 0; s < 8; ++s) v += Tg[(b2*8+s)*2 + e];
    if (cg < 80){
      A.out_before[((size_t)b2*256 + tt)*80 + cg] = v;
      A.before_t[((size_t)b2*80 + cg)*256 + tt] = v;
    } else if (cg == 80){
      A.out_logits[(size_t)b2*256 + tt] = v;
    }
  }
}

// ---- gpre1(tp): one block = 8 units (32 gate-cols), K=256 over pre(tp) ----
// NOTE: pre_all rows are batch-major at stride 65536 -> MUST use stage_pre.
__device__ __forceinline__ void gp1_body(const Args& A, int tp, int m2, int tid,
                                         float* Xl, const float* Wp4){
  stage_pre(A.pre_all + (size_t)tp*256, Xl, tid);
  int q = tid & 7, b = tid >> 3;
  v4f a0={0,0,0,0}, a1={0,0,0,0}, a2={0,0,0,0}, a3={0,0,0,0};
  const float* xr = Xl + b*260;
  #pragma unroll 8
  for (int jq = 0; jq < 64; ++jq){
    v4f xv = *(const v4f*)&xr[jq*4];
    a0 += xv * (*(const v4f*)&Wp4[jq*128 + q*4]);
    a1 += xv * (*(const v4f*)&Wp4[jq*128 + (q+8)*4]);
    a2 += xv * (*(const v4f*)&Wp4[jq*128 + (q+16)*4]);
    a3 += xv * (*(const v4f*)&Wp4[jq*128 + (q+24)*4]);
  }
  float* dst = A.gpre1 + (tp&1)*65536 + b*2048 + m2*32;
  cst(&dst[q],      hsum(a0));
  cst(&dst[q + 8],  hsum(a1));
  cst(&dst[q + 16], hsum(a2));
  cst(&dst[q + 24], hsum(a3));
}

// ---- attention body (per-b block), Gs already LDS-resident ----
__device__ __forceinline__ void att_body(const Args& A, int t, int b, int tid, float* L){
  const float* Gs = L + L_GS;
  float* awin = L + L_AW;
  float* pL   = L + L_PL;
  float* decs = L + L_DEC;
  float* red  = L + L_RED;
  int par = t & 1;
  int il = A.ilens[b];
  for (int i = tid; i < 288; i += 256){
    int tt = i - 15;
    float v = 0.f;
    if ((unsigned)tt < 256u)
      v = t ? A.out_aws[((size_t)b*256 + (t-1))*256 + tt]       // block-local, cached
            : ((tt < il) ? 1.0f/(float)il : 0.f);
    awin[i] = v;
  }
  if (tid < 128) decs[tid] = cld(&A.dec[b*128 + tid]);          // cross-block (small)
  __syncthreads();
  float gb = A.g_b[0];
  int dg = tid & 7, ttg = tid >> 3;
  int d0 = dg*16, tt0 = ttg*8;
  float ebuf[8];
  #pragma unroll
  for (int h = 0; h < 2; ++h){
    int ttb = tt0 + h*4;
    float aw[34];
    #pragma unroll
    for (int i = 0; i < 34; ++i) aw[i] = awin[ttb + i];
    v4f acc[4][4];
    #pragma unroll
    for (int i = 0; i < 4; ++i)
      #pragma unroll
      for (int r = 0; r < 4; ++r) acc[i][r] = (v4f){0.f,0.f,0.f,0.f};
    #pragma unroll
    for (int k = 0; k < 31; ++k){
      const float* gp = &Gs[k*128 + d0];
      v4f g0 = *(const v4f*)&gp[0],  g1 = *(const v4f*)&gp[4];
      v4f g2 = *(const v4f*)&gp[8],  g3 = *(const v4f*)&gp[12];
      #pragma unroll
      for (int i = 0; i < 4; ++i){
        float a = aw[i + k];
        acc[i][0] += g0*a; acc[i][1] += g1*a; acc[i][2] += g2*a; acc[i][3] += g3*a;
      }
    }
    #pragma unroll
    for (int i = 0; i < 4; ++i){
      int tt = ttb + i;
      const float* ep = A.enc_proj + ((size_t)b*256 + tt)*128 + d0;
      float s = 0.f;
      #pragma unroll
      for (int r = 0; r < 4; ++r){
        v4f v = acc[i][r] + *(const v4f*)&ep[r*4] + *(const v4f*)&decs[d0 + r*4];
        v4f gv = *(const v4f*)&A.g_w[d0 + r*4];
        s += tanhf(v.x)*gv.x + tanhf(v.y)*gv.y + tanhf(v.z)*gv.z + tanhf(v.w)*gv.w;
      }
      s += __shfl_xor(s,1); s += __shfl_xor(s,2); s += __shfl_xor(s,4);
      ebuf[h*4+i] = s;
    }
  }
  if (dg == 0){
    #pragma unroll
    for (int i = 0; i < 8; ++i){
      int tt = tt0 + i;
      float e = ebuf[i] + gb;
      pL[tt] = (tt < il) ? expf(2.0f*e) : 0.0f;
    }
  }
  __syncthreads();
  float pv = pL[tid];
  {
    float v = pv;
    v += __shfl_xor(v,1); v += __shfl_xor(v,2); v += __shfl_xor(v,4);
    v += __shfl_xor(v,8); v += __shfl_xor(v,16); v += __shfl_xor(v,32);
    if ((tid & 63) == 0) red[tid>>6] = v;
  }
  __syncthreads();
  float inv = 1.0f/(red[0]+red[1]+red[2]+red[3]);
  A.out_aws[((size_t)b*256 + t)*256 + tid] = pv*inv;             // block-local + output
  float a0 = 0.f, a1 = 0.f;
  const float* ez = A.enc_z + ((size_t)b*256)*512 + tid;
  #pragma unroll 16
  for (int q = 0; q < 256; ++q){
    float p = pL[q];
    a0 += p*ez[(size_t)q*512];
    a1 += p*ez[(size_t)q*512 + 256];
  }
  float* ac = A.att_c + par*16384 + b*512;
  cst(&ac[tid], a0*inv);                                        // single sc1 copy
  cst(&ac[tid + 256], a1*inv);
}

// ---- L0 gates + z0/c0 update (att_c from XCD L2 buffer) ----
__device__ __forceinline__ void l0_body(const Args& A, int par, int blk, int tid,
                                        float* Xl, float* Tg, const float* W4,
                                        const float* xb){
  const float* acb = xb + XB_AC + par*16384;
  v4f a0={0,0,0,0}, a1={0,0,0,0};
  stage256x(acb, 0, Xl, tid);   gemmK256(W4,        Xl, tid, a0, a1);
  stage256x(acb, 256, Xl, tid); gemmK256(W4 + 4096, Xl, tid, a0, a1);
  int q = tid & 7, b = tid >> 3;
  __syncthreads();
  Tg[b*16 + q]     = hsum(a0);
  Tg[b*16 + q + 8] = hsum(a1);
  __syncthreads();
  if (tid < 128){
    int b2 = tid >> 2, ul = tid & 3;
    int u = blk*4 + ul;
    float gi = Tg[b2*16 + ul*4 + 0];
    float gf = Tg[b2*16 + ul*4 + 1];
    float gg = Tg[b2*16 + ul*4 + 2];
    float go = Tg[b2*16 + ul*4 + 3];
    v4f p1 = cld4(&A.gpre1[par*65536 + b2*2048 + u*4]);          // disjoint sc1
    float zo = cld(&A.z0[b2*512 + u]);
    CWAIT();
    v4f p0 = *(const v4f*)&A.gpre0[b2*2048 + u*4];               // block-local
    v4f bs = *(const v4f*)&A.biasP0[u*4];
    gi += p0.x + p1.x + bs.x; gf += p0.y + p1.y + bs.y;
    gg += p0.z + p1.z + bs.z; go += p0.w + p1.w + bs.w;
    float co = A.c0g[b2*512 + u];                                // block-local
    float c2 = sigf(gf)*co + sigf(gi)*tanhf(gg);
    float h  = sigf(go)*tanhf(c2);
    A.c0g[b2*512 + u] = 0.1f*co + 0.9f*c2;
    cst(&A.z0[b2*512 + u], 0.1f*zo + 0.9f*h);                    // single sc1 copy
  }
}

// ---- LSTM1 + z1/c1 update (z0/z1prev from XCD L2 buffers) ----
__device__ __forceinline__ void lstm1_body(const Args& A, int par, int m, int tid,
                                           float* Xl, float* Tg, const float* W4,
                                           const float* xb){
  const float* z0b = xb + XB_Z0;
  const float* z1b = xb + XB_Z1 + (par^1)*16384;
  v4f a0={0,0,0,0}, a1={0,0,0,0};
  stage256x(z0b, 0,   Xl, tid); gemmK256(W4,         Xl, tid, a0, a1);
  stage256x(z0b, 256, Xl, tid); gemmK256(W4 + 4096,  Xl, tid, a0, a1);
  stage256x(z1b, 0,   Xl, tid); gemmK256(W4 + 8192,  Xl, tid, a0, a1);
  stage256x(z1b, 256, Xl, tid); gemmK256(W4 + 12288, Xl, tid, a0, a1);
  int q = tid & 7, b = tid >> 3;
  __syncthreads();
  Tg[b*16 + q]     = hsum(a0);
  Tg[b*16 + q + 8] = hsum(a1);
  __syncthreads();
  if (tid < 128){
    int b2 = tid >> 2, ul = tid & 3;
    int u = m*4 + ul;
    float gi = Tg[b2*16 + ul*4 + 0];
    float gf = Tg[b2*16 + ul*4 + 1];
    float gg = Tg[b2*16 + ul*4 + 2];
    float go = Tg[b2*16 + ul*4 + 3];
    v4f bs = *(const v4f*)&A.biasP1[u*4];
    gi += bs.x; gf += bs.y; gg += bs.z; go += bs.w;
    float co = A.c1g[b2*512 + u];                                // block-local
    float zo = cld(&A.z1[(par^1)*16384 + b2*512 + u]);
    float c2 = sigf(gf)*co + sigf(gi)*tanhf(gg);
    float h  = sigf(go)*tanhf(c2);
    A.c1g[b2*512 + u] = 0.1f*co + 0.9f*c2;
    cst(&A.z1[par*16384 + b2*512 + u], 0.1f*zo + 0.9f*h);        // single sc1 copy
  }
}

// ---- gpre0 + dec prefetch for next step (z0 from XCD L2 buffer) ----
__device__ __forceinline__ void gpre0_body(const Args& A, int blk, int tid,
                                           float* Xl, const float* W4, const float* Wd,
                                           const float* xb){
  const float* z0b = xb + XB_Z0;
  v4f a0={0,0,0,0}, a1={0,0,0,0};
  v4f dd4={0,0,0,0};
  int q = tid & 7, b = tid >> 3;
  stage256x(z0b, 0, Xl, tid);
  gemmK256(W4, Xl, tid, a0, a1);
  if (blk < 32){
    #pragma unroll 8
    for (int i = 0; i < 32; ++i){
      int kl = q*32 + i;
      dd4 += Xl[b*260 + kl] * (*(const v4f*)&Wd[kl*4]);
    }
  }
  stage256x(z0b, 256, Xl, tid);
  gemmK256(W4 + 4096, Xl, tid, a0, a1);
  if (blk < 32){
    #pragma unroll 8
    for (int i = 0; i < 32; ++i){
      int kl = q*32 + i;
      dd4 += Xl[b*260 + kl] * (*(const v4f*)&Wd[(256+kl)*4]);
    }
    #pragma unroll
    for (int m = 1; m < 8; m <<= 1){
      dd4.x += __shfl_xor(dd4.x, m); dd4.y += __shfl_xor(dd4.y, m);
      dd4.z += __shfl_xor(dd4.z, m); dd4.w += __shfl_xor(dd4.w, m);
    }
    if (q == 0){
      float* dp = &A.dec[b*128 + blk*4];
      cst(&dp[0], dd4.x); cst(&dp[1], dd4.y);
      cst(&dp[2], dd4.z); cst(&dp[3], dd4.w);
    }
  }
  float* dst = A.gpre0 + b*2048 + blk*16;                        // block-local
  dst[q]     = hsum(a0);
  dst[q + 8] = hsum(a1);
}

// ---- grid barrier: fence-free (cross-block data uses sc1 accesses) ----
#define COLL 255
__device__ __forceinline__ void gsync(unsigned* bars, unsigned idx){
  unsigned* go = bars + 384;
  asm volatile("" ::: "memory");
  __syncthreads();
  if (threadIdx.x == 0)
    __hip_atomic_store(&bars[blockIdx.x], idx, __ATOMIC_RELAXED, __HIP_MEMORY_SCOPE_AGENT);
  if (blockIdx.x == COLL){
    while (__hip_atomic_load(&bars[threadIdx.x], __ATOMIC_RELAXED, __HIP_MEMORY_SCOPE_AGENT) < idx)
      __builtin_amdgcn_s_sleep(1);
    __syncthreads();
    if (threadIdx.x == 0)
      __hip_atomic_store(go, idx, __ATOMIC_RELAXED, __HIP_MEMORY_SCOPE_AGENT);
  }
  if (threadIdx.x == 0){
    while (__hip_atomic_load(go, __ATOMIC_RELAXED, __HIP_MEMORY_SCOPE_AGENT) < idx)
      __builtin_amdgcn_s_sleep(1);
  }
  __syncthreads();
  asm volatile("" ::: "memory");
}

// ---------------- persistent loop (grid=256, 1 block/CU by LDS) ----------------
// roles: blk 0-31: att (A) + L0 (B) + gpre0/dec (C)
//        blk 32-127: L0 (B) + gpre0 (C)
//        blk 128-191: gpre1(t+1) (A) + LSTM1 (C)
//        blk 192-232: out(t-1) (A) + LSTM1 (C)
//        blk 233-255: LSTM1 (C)
// Broadcast state (att_c/z0/z1) crosses XCDs ONCE per phase via relay();
// consumers read the XCD-local L2 copy with sc0 loads.
__global__ void __launch_bounds__(256, 1) k_loop(Args A){
  extern __shared__ float L[];
  float* Xl = L + L_XL;
  float* Tg = L + L_TG;
  float* W4 = L + L_W4;
  float* WX = L + L_WX;
  int* Li = (int*)L;
  int blk = blockIdx.x, tid = threadIdx.x;
  unsigned* ctr = A.bars;

  int xcd;
  asm volatile("s_getreg_b32 %0, hwreg(HW_REG_XCC_ID)" : "=s"(xcd));
  xcd &= 7;

  // ---- one-time LDS weight residency ----
  if (blk < 128){
    const float* src = A.W0pack + (size_t)blk*16384;
    for (int i = tid*4; i < 16384; i += 1024) *(v4f*)&W4[i] = *(const v4f*)&src[i];
    if (blk < 32){
      const float* sd = A.Wdpack + (size_t)blk*2048;
      for (int i = tid; i < 2048; i += 256) WX[i] = sd[i];
      for (int i = tid; i < 3968; i += 256) L[L_GS + i] = A.G[i];
    }
  } else {
    const float* src = A.W1pack + (size_t)(blk-128)*16384;
    for (int i = tid*4; i < 16384; i += 1024) *(v4f*)&W4[i] = *(const v4f*)&src[i];
    if (blk < 192){
      const float* sp = A.Wp1pack + (size_t)(blk-128)*8192;
      for (int i = tid*4; i < 8192; i += 1024) *(v4f*)&WX[i] = *(const v4f*)&sp[i];
    } else if (blk < 233){
      const float* sf = A.WFpack + (size_t)(blk-192)*2048;
      for (int i = tid; i < 2048; i += 256) WX[i] = sf[i];
    }
  }
  if (tid == 0){
    unsigned r = __hip_atomic_fetch_add(&ctr[400+xcd], 1u,
                                        __ATOMIC_RELAXED, __HIP_MEMORY_SCOPE_AGENT);
    Li[L_MISC] = (int)r;
  }
  __syncthreads();
  int rank = Li[L_MISC];

  unsigned sidx = 0;
  // bootstrap gpre1(0) (parity 0)
  if (blk >= 128 && blk < 192) gp1_body(A, 0, blk-128, tid, Xl, WX);
  gsync(A.bars, ++sidx);

  if (tid == 0)
    Li[L_MISC+1] = (int)__hip_atomic_load(&ctr[400+xcd],
                                          __ATOMIC_RELAXED, __HIP_MEMORY_SCOPE_AGENT);
  __syncthreads();
  int R = Li[L_MISC+1];
  float* xb = A.xbuf + (size_t)xcd*XB_STRIDE;
  unsigned ev = 0;

  for (int t = 0; t < LSEQ; ++t){
    int par = t & 1;
    // ---- phase A: relay z1[par^1]; attention | gpre1(t+1) | out(t-1) ----
    relay(ctr, A.z1 + (par^1)*16384, xb + XB_Z1 + (par^1)*16384, xcd, rank, R, ++ev, tid);
    if (blk < 32){
      att_body(A, t, blk, tid, L);
    } else if (blk >= 128 && blk < 192){
      if (t < 255) gp1_body(A, t+1, blk-128, tid, Xl, WX);
    } else if (blk >= 192 && blk < 233){
      if (t > 0){
        int pb = par^1;
        out_phase(A, xb + XB_Z1 + pb*16384, xb + XB_AC + pb*16384,
                  t-1, blk-192, tid, Xl, Tg, WX);
      }
    }
    gsync(A.bars, ++sidx);
    // ---- phase B: relay att_c[par]; L0 gates + z0 update ----
    relay(ctr, A.att_c + par*16384, xb + XB_AC + par*16384, xcd, rank, R, ++ev, tid);
    if (blk < 128) l0_body(A, par, blk, tid, Xl, Tg, W4, xb);
    gsync(A.bars, ++sidx);
    // ---- phase C: relay z0; LSTM1 | gpre0/dec prefetch ----
    relay(ctr, A.z0, xb + XB_Z0, xcd, rank, R, ++ev, tid);
    if (blk >= 128) lstm1_body(A, par, blk-128, tid, Xl, Tg, W4, xb);
    else if (t < 255) gpre0_body(A, blk, tid, Xl, W4 + 8192, WX, xb);
    gsync(A.bars, ++sidx);
  }
  // ---- tail: refresh z1[1] (written at C(255)), then out(255) ----
  relay(ctr, A.z1 + 16384, xb + XB_Z1 + 16384, xcd, rank, R, ++ev, tid);
  if (blk >= 192 && blk < 233)
    out_phase(A, xb + XB_Z1 + 16384, xb + XB_AC + 16384, 255, blk-192, tid, Xl, Tg, WX);
}

// ---------------- postnet conv (kernel=5, pad=2) as tiled GEMM ----------------
__global__ void __launch_bounds__(256) k_conv(const float* __restrict__ in,
                       const float* __restrict__ Wt,
                       const float* __restrict__ sc, const float* __restrict__ sh,
                       float* __restrict__ out0, const float* __restrict__ before,
                       float* __restrict__ after, int C, int N, int mode)
{
  __shared__ __align__(16) float As[16][64];
  __shared__ __align__(16) float Bs[16][64];
  int bx = blockIdx.x;
  int b = bx >> 2, l0 = (bx & 3)*64;
  int n0 = blockIdx.y*64;
  int tid = threadIdx.x, tx = tid & 15, ty = tid >> 4;
  float acc[4][4];
  #pragma unroll
  for (int i = 0; i < 4; ++i)
    #pragma unroll
    for (int j = 0; j < 4; ++j) acc[i][j] = 0.f;
  for (int k = 0; k < 5; ++k){
    int shift = k - 2;
    for (int c0 = 0; c0 < C; c0 += 16){
      #pragma unroll
      for (int i = 0; i < 4; ++i){
        int e = tid + i*256; int cc = e >> 6, ll = e & 63;
        int l = l0 + ll + shift;
        As[cc][ll] = ((unsigned)l < 256u) ? in[((size_t)(b*C + c0+cc))*256 + l] : 0.f;
        int n = n0 + ll;
        Bs[cc][ll] = (n < N) ? Wt[((size_t)k*C + c0+cc)*(size_t)N + n] : 0.f;
      }
      __syncthreads();
      #pragma unroll
      for (int cc = 0; cc < 16; ++cc){
        const float4 av = *reinterpret_cast<const float4*>(&As[cc][ty<<2]);
        const float4 bv = *reinterpret_cast<const float4*>(&Bs[cc][tx<<2]);
        acc[0][0]+=av.x*bv.x; acc[0][1]+=av.x*bv.y; acc[0][2]+=av.x*bv.z; acc[0][3]+=av.x*bv.w;
        acc[1][0]+=av.y*bv.x; acc[1][1]+=av.y*bv.y; acc[1][2]+=av.y*bv.z; acc[1][3]+=av.y*bv.w;
        acc[2][0]+=av.z*bv.x; acc[2][1]+=av.z*bv.y; acc[2][2]+=av.z*bv.z; acc[2][3]+=av.z*bv.w;
        acc[3][0]+=av.w*bv.x; acc[3][1]+=av.w*bv.y; acc[3][2]+=av.w*bv.z; acc[3][3]+=av.w*bv.w;
      }
      __syncthreads();
    }
  }
  #pragma unroll
  for (int i = 0; i < 4; ++i){
    int l = l0 + (ty<<2) + i;
    #pragma unroll
    for (int j = 0; j < 4; ++j){
      int n = n0 + (tx<<2) + j;
      if (n < N){
        float v = sc[n]*acc[i][j] + sh[n];
        if (mode == 0){
          out0[((size_t)(b*N + n))*256 + l] = tanhf(v);
        } else {
          size_t ob2 = ((size_t)b*256 + l)*80 + n;
          after[ob2] = before[ob2] + v;
        }
      }
    }
  }
}

extern "C" void kernel_launch(void* const* d_in, const int* in_sizes, int n_in,
                              void* d_out, int out_size, void* d_ws, size_t ws_size,
                              hipStream_t stream) {
  Args A;
  A.enc_z = (const float*)d_in[0];  A.ys = (const float*)d_in[1];
  A.ilens = (const int*)d_in[3];
  A.W_enc = (const float*)d_in[4];  A.b_enc = (const float*)d_in[5];
  A.W_dec = (const float*)d_in[6];  A.loc_kernel = (const float*)d_in[7];
  A.W_att = (const float*)d_in[8];  A.g_w = (const float*)d_in[9];  A.g_b = (const float*)d_in[10];
  A.Wp0 = (const float*)d_in[11];   A.bp0 = (const float*)d_in[12];
  A.Wp1 = (const float*)d_in[13];   A.bp1 = (const float*)d_in[14];
  A.Wih0 = (const float*)d_in[15];  A.Whh0 = (const float*)d_in[16];
  A.bih0 = (const float*)d_in[17];  A.bhh0 = (const float*)d_in[18];
  A.Wih1 = (const float*)d_in[19];  A.Whh1 = (const float*)d_in[20];
  A.bih1 = (const float*)d_in[21];  A.bhh1 = (const float*)d_in[22];
  A.Wf = (const float*)d_in[23];    A.bf = (const float*)d_in[24];
  A.Wq = (const float*)d_in[25];    A.bq = (const float*)d_in[26];
  A.pk0 = (const float*)d_in[27];   A.pb0 = (const float*)d_in[28];
  A.bg0 = (const float*)d_in[29];   A.bb0 = (const float*)d_in[30];
  A.pk1 = (const float*)d_in[31];   A.pb1 = (const float*)d_in[32];
  A.bg1 = (const float*)d_in[33];   A.bb1 = (const float*)d_in[34];
  A.pk2 = (const float*)d_in[35];   A.pb2 = (const float*)d_in[36];
  A.bg2 = (const float*)d_in[37];   A.bb2 = (const float*)d_in[38];

  float* ws = (float*)d_ws;
  size_t off = 0;
  auto alloc = [&](size_t n){ float* p = ws + off; off += n; return p; };
  A.enc_proj   = alloc(1048576);
  A.pre_tmp    = alloc(2097152);
  A.pre_all    = alloc(2097152);
  A.G          = alloc(3968);
  A.dec        = alloc(4096);
  A.att_c      = alloc(32768);
  A.z0         = alloc(16384);
  A.z1         = alloc(32768);
  A.c0g        = alloc(16384);
  A.c1g        = alloc(16384);
  A.gpre0      = alloc(65536);
  A.gpre1      = alloc(131072);
  A.biasP0     = alloc(2048);
  A.biasP1     = alloc(2048);
  A.before_t   = alloc(655360);
  A.h0         = alloc(4194304);
  A.h1         = alloc(4194304);
  A.Wt0        = alloc(204800);
  A.Wt1        = alloc(1310720);
  A.Wt2        = alloc(204800);
  A.s0 = alloc(512); A.t0s = alloc(512);
  A.s1 = alloc(512); A.t1s = alloc(512);
  A.s2 = alloc(128); A.t2s = alloc(128);
  A.bars = (unsigned*)alloc(512);
  // weight packs alias the postnet activation buffers (consumed by k_loop
  // before postnet runs; k_init refills them at the start of every replay)
  A.W0pack  = A.h0;                       // 128*16384 = 2097152
  A.W1pack  = A.h0 + 2097152;             // 2097152
  A.Wp1pack = A.h1;                       // 64*8192 = 524288
  A.WFpack  = A.h1 + 524288;              // 41*2048 = 83968
  A.Wdpack  = A.h1 + 524288 + 83968;      // 32*2048 = 65536
  // per-XCD staging buffers in h1's tail (dead during k_loop; conv-2 writes h1
  // strictly after k_loop retires). 8 * 81920 = 655360, end 1329152 < 4194304.
  A.xbuf    = A.h1 + 673792;

  float* out = (float*)d_out;
  A.out_after  = out;
  A.out_before = out + 655360;
  A.out_logits = out + 1310720;
  A.out_aws    = out + 1318912;

  hipFuncSetAttribute((const void*)k_loop,
                      hipFuncAttributeMaxDynamicSharedMemorySize, DYN_L);

  k_init<<<dim3(1024), dim3(256), 0, stream>>>(A);
  k_encproj<<<dim3(256), dim3(256), 0, stream>>>(A);
  k_pre0<<<dim3(256), dim3(256), 0, stream>>>(A);
  k_pre1<<<dim3(256), dim3(256), 0, stream>>>(A);

  // Plain launch: grid=256 with 130.6 KiB dynamic LDS forces 1 block/CU on
  // 256 CUs -> all blocks co-resident, so the flag-array grid barrier is safe.
  k_loop<<<dim3(256), dim3(256), DYN_L, stream>>>(A);

  k_conv<<<dim3(128,8), dim3(256), 0, stream>>>(A.before_t, A.Wt0, A.s0, A.t0s, A.h0, nullptr, nullptr, 80, 512, 0);
  k_conv<<<dim3(128,8), dim3(256), 0, stream>>>(A.h0, A.Wt1, A.s1, A.t1s, A.h1, nullptr, nullptr, 512, 512, 0);
  k_conv<<<dim3(128,2), dim3(256), 0, stream>>>(A.h1, A.Wt2, A.s2, A.t2s, nullptr, A.out_before, A.out_after, 512, 80, 1);
}

// Round 10
// 44505.521 us; speedup vs baseline: 2.0648x; 2.0648x over previous
//
#include <hip/hip_runtime.h>
#include <cstdint>

#define LSEQ 256
#define BN_INV 0.99999500003750f

typedef float v4f __attribute__((ext_vector_type(4)));

#define DYN_L 133760   // 33440 floats: Xl 8320 | Tg 544 | W4 16384 | WX 2048/8192 | attn region

// LDS float offsets for the persistent kernel
#define L_XL   0
#define L_TG   8320
#define L_W4   8864      // 16384 floats: [Wih|Whh] image
#define L_WX   25248     // Wd (2048) | Wp1s (8192) | WFs (2048)
#define L_GS   27296     // 3968 (attn blocks only; after their 2048-float Wd)
#define L_AW   31264     // 288
#define L_PL   31552     // 256
#define L_DEC  31808     // 128
#define L_RED  31936     // 4  -> end 31940 (< 33440)

// z0 rotation: slot s at z0rA[s] for s<214, else z0rB[s-214]. 257 slots, each
// 16384 floats. Addresses are NEVER reused => consumers may use plain cached
// loads with no stale-line hazard; producers write-through with sc1.
#define ZSLOT_A 214

struct Args {
  const float *enc_z, *ys;
  const int* ilens;
  const float *W_enc, *b_enc, *W_dec, *loc_kernel, *W_att, *g_w, *g_b;
  const float *Wp0, *bp0, *Wp1, *bp1;
  const float *Wih0, *Whh0, *bih0, *bhh0, *Wih1, *Whh1, *bih1, *bhh1;
  const float *Wf, *bf, *Wq, *bq;
  const float *pk0,*pb0,*bg0,*bb0,*pk1,*pb1,*bg1,*bb1,*pk2,*pb2,*bg2,*bb2;
  float *enc_proj, *pre_tmp, *pre_all, *G, *dec, *att_c;
  float *z0, *z1, *c0g, *c1g, *gpre0, *gpre1, *biasP0, *biasP1;
  float *before_t, *h0, *h1, *Wt0, *Wt1, *Wt2, *s0, *t0s, *s1, *t1s, *s2, *t2s;
  float *W0pack, *W1pack, *Wp1pack, *WFpack, *Wdpack;
  float *z0rA, *z0rB;   // rotating z0 slots (h1 tail / dead pre_tmp)
  float *out_after, *out_before, *out_logits, *out_aws;
  unsigned *bars;   // [0..256) per-block arrive flags, [384] go flag
};

__device__ __forceinline__ float sigf(float x){ return 1.0f/(1.0f+expf(-x)); }
__device__ __forceinline__ float hsum(const v4f& v){ return v.x+v.y+v.z+v.w; }

__device__ __forceinline__ float* zslot(const Args& A, int s){
  return (s < ZSLOT_A) ? A.z0rA + (size_t)s*16384
                       : A.z0rB + (size_t)(s - ZSLOT_A)*16384;
}

// ---- coherent (device-scope) accessors for cross-block buffers ----
__device__ __forceinline__ float cld(const float* p){
  return __hip_atomic_load(p, __ATOMIC_RELAXED, __HIP_MEMORY_SCOPE_AGENT);
}
__device__ __forceinline__ void cst(float* p, float v){
  __hip_atomic_store(p, v, __ATOMIC_RELAXED, __HIP_MEMORY_SCOPE_AGENT);
}
// wide pipelined coherent load (bypasses stale caches; drain with CWAIT)
__device__ __forceinline__ v4f cld4(const float* p){
  v4f v;
  asm volatile("global_load_dwordx4 %0, %1, off sc0 sc1" : "=v"(v) : "v"(p));
  return v;
}
#define CWAIT() do { asm volatile("s_waitcnt vmcnt(0)" ::: "memory"); \
                     __builtin_amdgcn_sched_barrier(0); } while(0)

// ---------------- init: precomputes + per-block weight packs ----------------
__global__ void k_init(Args A){
  int tid0 = blockIdx.x*blockDim.x + threadIdx.x;
  int stride = gridDim.x*blockDim.x;
  for (int i = tid0; i < 512; i += stride) A.bars[i] = 0u;
  for (int i = tid0; i < 16384; i += stride) A.z0rA[i] = 0.f;   // rot slot 0
  for (int i = tid0; i < 31*128; i += stride){
    int k = i >> 7, d = i & 127;
    float s = 0.f;
    for (int c = 0; c < 32; ++c) s += A.W_att[c*128+d]*A.loc_kernel[c*31+k];
    A.G[i] = s;
  }
  for (int i = tid0; i < 2048; i += stride){
    int u = i & 511, g = i >> 9;
    A.biasP0[u*4+g] = A.bih0[i]+A.bhh0[i];
    A.biasP1[u*4+g] = A.bih1[i]+A.bhh1[i];
  }
  for (int i = tid0; i < 16384; i += stride){ A.z0[i]=0.f; A.c0g[i]=0.f; A.c1g[i]=0.f; }
  for (int i = tid0; i < 32768; i += stride) A.z1[i]=0.f;
  for (int i = tid0; i < 65536; i += stride) A.gpre0[i]=0.f;
  for (int i = tid0; i < 4096; i += stride) A.dec[i]=0.f;
  for (int i = tid0; i < 512; i += stride){
    float s = A.bg0[i]*BN_INV; A.s0[i]=s; A.t0s[i]=s*A.pb0[i]+A.bb0[i];
    float u = A.bg1[i]*BN_INV; A.s1[i]=u; A.t1s[i]=u*A.pb1[i]+A.bb1[i];
  }
  for (int i = tid0; i < 80; i += stride){
    float s = A.bg2[i]*BN_INV; A.s2[i]=s; A.t2s[i]=s*A.pb2[i]+A.bb2[i];
  }
  for (int i = tid0; i < 5*80*512; i += stride){
    int k = i/(80*512); int r = i - k*(80*512); int c = r>>9, n = r&511;
    A.Wt0[i] = A.pk0[(n*80+c)*5+k];
  }
  for (int i = tid0; i < 5*512*512; i += stride){
    int k = i/(512*512); int r = i - k*(512*512); int c = r>>9, n = r&511;
    A.Wt1[i] = A.pk1[(n*512+c)*5+k];
  }
  for (int i = tid0; i < 5*512*80; i += stride){
    int k = i/(512*80); int r = i - k*(512*80); int c = r/80, n = r - c*80;
    A.Wt2[i] = A.pk2[(n*512+c)*5+k];
  }
  // ---- per-block weight packs (LDS image order => coalesced reload) ----
  for (int i = tid0; i < 128*16384; i += stride){
    int blk = i >> 14, idx = i & 16383;
    int kq = idx >> 6, rem = idx & 63, p = rem >> 2, kl = rem & 3;
    int k = kq*4 + kl;
    int gcol = (p & 3)*512 + blk*4 + (p >> 2);
    A.W0pack[i] = (k < 512) ? A.Wih0[(size_t)k*2048 + gcol]
                            : A.Whh0[(size_t)(k-512)*2048 + gcol];
  }
  for (int i = tid0; i < 128*16384; i += stride){
    int blk = i >> 14, idx = i & 16383;
    int kq = idx >> 6, rem = idx & 63, p = rem >> 2, kl = rem & 3;
    int k = kq*4 + kl;
    int gcol = (p & 3)*512 + blk*4 + (p >> 2);
    A.W1pack[i] = (k < 512) ? A.Wih1[(size_t)k*2048 + gcol]
                            : A.Whh1[(size_t)(k-512)*2048 + gcol];
  }
  for (int i = tid0; i < 64*8192; i += stride){
    int m = i >> 13, idx = i & 8191;
    int kq = idx >> 7, rem = idx & 127, p = rem >> 2, kl = rem & 3;
    int k = kq*4 + kl;
    int gcol = (p & 3)*512 + m*8 + (p >> 2);
    A.Wp1pack[i] = A.Wih0[(size_t)(512+k)*2048 + gcol];
  }
  for (int i = tid0; i < 41*2048; i += stride){
    int blk = i >> 11, k2 = i & 2047;
    int k = k2 >> 1, e = k2 & 1, c = blk*2 + e;
    A.WFpack[i] = (c < 80) ? A.Wf[(size_t)k*80 + c] : A.Wq[k];
  }
  for (int i = tid0; i < 32*2048; i += stride){
    int blk = i >> 11, j = i & 2047;
    int k = j >> 2, c = j & 3;
    A.Wdpack[i] = A.W_dec[(size_t)k*128 + blk*4 + c];
  }
}

// ---------------- enc_proj ----------------
__global__ void __launch_bounds__(256) k_encproj(Args A){
  __shared__ __align__(16) float As[32][128];
  int m0 = blockIdx.x*32;
  int tid = threadIdx.x;
  int d = tid & 127, half = tid >> 7;
  float acc[16];
  #pragma unroll
  for (int r = 0; r < 16; ++r) acc[r] = 0.f;
  for (int j0 = 0; j0 < 512; j0 += 128){
    for (int i = 0; i < 16; ++i){
      int e = tid + i*256; int r = e >> 7, j = e & 127;
      As[r][j] = A.enc_z[(size_t)(m0+r)*512 + j0 + j];
    }
    __syncthreads();
    for (int j = 0; j < 128; ++j){
      float w = A.W_enc[(size_t)(j0+j)*128 + d];
      #pragma unroll
      for (int r = 0; r < 16; ++r) acc[r] += As[half*16+r][j]*w;
    }
    __syncthreads();
  }
  float be = A.b_enc[d];
  for (int r = 0; r < 16; ++r)
    A.enc_proj[(size_t)(m0+half*16+r)*128 + d] = acc[r] + be;
}

// ---------------- prenet ----------------
__global__ void __launch_bounds__(256) k_pre0(Args A){
  __shared__ float As[32][80];
  int m0 = blockIdx.x*32, tid = threadIdx.x;
  for (int e = tid; e < 2560; e += 256){
    int r = e/80, o = e - r*80;
    int row = m0+r; int l = row & 255, b = row >> 8;
    As[r][o] = (l==0) ? 0.f : A.ys[((size_t)b*256 + (l-1))*80 + o];
  }
  __syncthreads();
  float acc[32];
  #pragma unroll
  for (int r = 0; r < 32; ++r) acc[r] = 0.f;
  for (int o = 0; o < 80; ++o){
    float w = A.Wp0[o*256 + tid];
    #pragma unroll
    for (int r = 0; r < 32; ++r) acc[r] += As[r][o]*w;
  }
  float bb = A.bp0[tid];
  for (int r = 0; r < 32; ++r){
    float v = acc[r]+bb;
    A.pre_tmp[(size_t)(m0+r)*256 + tid] = v>0.f?v:0.f;
  }
}

__global__ void __launch_bounds__(256) k_pre1(Args A){
  __shared__ float As[32][256];
  int m0 = blockIdx.x*32, tid = threadIdx.x;
  for (int e = tid; e < 8192; e += 256){
    int r = e >> 8, j = e & 255;
    As[r][j] = A.pre_tmp[(size_t)(m0+r)*256 + j];
  }
  __syncthreads();
  float acc[32];
  #pragma unroll
  for (int r = 0; r < 32; ++r) acc[r] = 0.f;
  for (int j = 0; j < 256; ++j){
    float w = A.Wp1[j*256 + tid];
    #pragma unroll
    for (int r = 0; r < 32; ++r) acc[r] += As[r][j]*w;
  }
  float bb = A.bp1[tid];
  for (int r = 0; r < 32; ++r){
    float v = acc[r]+bb;
    A.pre_all[(size_t)(m0+r)*256 + tid] = v>0.f?v:0.f;
  }
}

// ---- stage 32 rows x 256 floats into LDS (pitch 260), normal cached loads ----
__device__ __forceinline__ void stage256(const float* base, int rowstride, int koff,
                                         float* Xl, int tid){
  v4f r0,r1,r2,r3,r4,r5,r6,r7;
  #define LDX(i,dst) { int f=tid+((i)<<8); int b=f>>6; int jq=f&63; \
      dst = *(const v4f*)(base + (size_t)b*rowstride + koff + jq*4); }
  LDX(0,r0) LDX(1,r1) LDX(2,r2) LDX(3,r3) LDX(4,r4) LDX(5,r5) LDX(6,r6) LDX(7,r7)
  #undef LDX
  __syncthreads();
  #define STX(i,src) { int f=tid+((i)<<8); int b=f>>6; int jq=f&63; \
      *(v4f*)&Xl[b*260 + jq*4] = src; }
  STX(0,r0) STX(1,r1) STX(2,r2) STX(3,r3) STX(4,r4) STX(5,r5) STX(6,r6) STX(7,r7)
  #undef STX
  __syncthreads();
}

// ---- coherent variant: pipelined dwordx4 sc0 sc1 loads + one explicit drain ----
__device__ __forceinline__ void stage256c(const float* base, int rowstride, int koff,
                                          float* Xl, int tid){
  v4f r0,r1,r2,r3,r4,r5,r6,r7;
  #define LDX(i,dst) { int f=tid+((i)<<8); int b=f>>6; int jq=f&63; \
      dst = cld4(base + (size_t)b*rowstride + koff + jq*4); }
  LDX(0,r0) LDX(1,r1) LDX(2,r2) LDX(3,r3) LDX(4,r4) LDX(5,r5) LDX(6,r6) LDX(7,r7)
  #undef LDX
  CWAIT();
  __syncthreads();
  #define STX(i,src) { int f=tid+((i)<<8); int b=f>>6; int jq=f&63; \
      *(v4f*)&Xl[b*260 + jq*4] = src; }
  STX(0,r0) STX(1,r1) STX(2,r2) STX(3,r3) STX(4,r4) STX(5,r5) STX(6,r6) STX(7,r7)
  #undef STX
  __syncthreads();
}

// ---- K=256 chunk gemm ----
__device__ __forceinline__ void gemmK256(const float* __restrict__ W4,
                                         const float* __restrict__ Xl,
                                         int tid, v4f& a0, v4f& a1){
  const int q = tid & 7, b = tid >> 3;
  const float* xr = Xl + b*260;
  #pragma unroll 8
  for (int jq = 0; jq < 64; ++jq){
    v4f xv = *(const v4f*)&xr[jq*4];
    v4f w0 = *(const v4f*)&W4[jq*64 + q*4];
    v4f w1 = *(const v4f*)&W4[jq*64 + (q+8)*4];
    a0 += xv*w0; a1 += xv*w1;
  }
}

// ---- out(tt): 2 cols of [Wf|Wq], K=1024 over [z1; att_c] ----
__device__ __forceinline__ void out_phase(const Args& A, const float* z1b, const float* acb,
                                          int tt, int ob, int tid, float* Xl, float* Tg,
                                          const float* WF){
  int b = tid >> 3, sub = tid & 7;
  float acc0 = 0.f, acc1 = 0.f;
  for (int pass = 0; pass < 4; ++pass){
    const float* src = (pass < 2) ? z1b : acb;
    stage256c(src, 512, (pass & 1)*256, Xl, tid);
    int kbase = pass*256;
    #pragma unroll 4
    for (int i = 0; i < 32; ++i){
      int k = sub + 8*i;
      float x = Xl[b*260 + k];
      acc0 += x*WF[(kbase+k)*2 + 0];
      acc1 += x*WF[(kbase+k)*2 + 1];
    }
    __syncthreads();
  }
  Tg[(b*8+sub)*2+0] = acc0; Tg[(b*8+sub)*2+1] = acc1;
  __syncthreads();
  if (tid < 64){
    int b2 = tid >> 1, e = tid & 1, cg = ob*2 + e;
    float v = (cg < 80) ? A.bf[cg] : A.bq[0];
    for (int s = 0; s < 8; ++s) v += Tg[(b2*8+s)*2 + e];
    if (cg < 80){
      A.out_before[((size_t)b2*256 + tt)*80 + cg] = v;
      A.before_t[((size_t)b2*80 + cg)*256 + tt] = v;
    } else if (cg == 80){
      A.out_logits[(size_t)b2*256 + tt] = v;
    }
  }
}

// ---- gpre1(tp): one block = 8 units (32 gate-cols), K=256 over pre(tp) ----
__device__ __forceinline__ void gp1_body(const Args& A, int tp, int m2, int tid,
                                         float* Xl, const float* Wp4){
  stage256(A.pre_all + (size_t)tp*256, 65536, 0, Xl, tid);   // pre_all: read-only, cached
  int q = tid & 7, b = tid >> 3;
  v4f a0={0,0,0,0}, a1={0,0,0,0}, a2={0,0,0,0}, a3={0,0,0,0};
  const float* xr = Xl + b*260;
  #pragma unroll 8
  for (int jq = 0; jq < 64; ++jq){
    v4f xv = *(const v4f*)&xr[jq*4];
    a0 += xv * (*(const v4f*)&Wp4[jq*128 + q*4]);
    a1 += xv * (*(const v4f*)&Wp4[jq*128 + (q+8)*4]);
    a2 += xv * (*(const v4f*)&Wp4[jq*128 + (q+16)*4]);
    a3 += xv * (*(const v4f*)&Wp4[jq*128 + (q+24)*4]);
  }
  float* dst = A.gpre1 + (tp&1)*65536 + b*2048 + m2*32;
  cst(&dst[q],      hsum(a0));
  cst(&dst[q + 8],  hsum(a1));
  cst(&dst[q + 16], hsum(a2));
  cst(&dst[q + 24], hsum(a3));
}

// ---- attention body (per-b block), Gs already LDS-resident ----
__device__ __forceinline__ void att_body(const Args& A, int t, int b, int tid, float* L){
  const float* Gs = L + L_GS;
  float* awin = L + L_AW;
  float* pL   = L + L_PL;
  float* decs = L + L_DEC;
  float* red  = L + L_RED;
  int par = t & 1;
  int il = A.ilens[b];
  for (int i = tid; i < 288; i += 256){
    int tt = i - 15;
    float v = 0.f;
    if ((unsigned)tt < 256u)
      v = t ? A.out_aws[((size_t)b*256 + (t-1))*256 + tt]       // block-local, cached
            : ((tt < il) ? 1.0f/(float)il : 0.f);
    awin[i] = v;
  }
  if (tid < 128) decs[tid] = cld(&A.dec[b*128 + tid]);          // cross-block
  __syncthreads();
  float gb = A.g_b[0];
  int dg = tid & 7, ttg = tid >> 3;
  int d0 = dg*16, tt0 = ttg*8;
  float ebuf[8];
  #pragma unroll
  for (int h = 0; h < 2; ++h){
    int ttb = tt0 + h*4;
    float aw[34];
    #pragma unroll
    for (int i = 0; i < 34; ++i) aw[i] = awin[ttb + i];
    v4f acc[4][4];
    #pragma unroll
    for (int i = 0; i < 4; ++i)
      #pragma unroll
      for (int r = 0; r < 4; ++r) acc[i][r] = (v4f){0.f,0.f,0.f,0.f};
    #pragma unroll
    for (int k = 0; k < 31; ++k){
      const float* gp = &Gs[k*128 + d0];
      v4f g0 = *(const v4f*)&gp[0],  g1 = *(const v4f*)&gp[4];
      v4f g2 = *(const v4f*)&gp[8],  g3 = *(const v4f*)&gp[12];
      #pragma unroll
      for (int i = 0; i < 4; ++i){
        float a = aw[i + k];
        acc[i][0] += g0*a; acc[i][1] += g1*a; acc[i][2] += g2*a; acc[i][3] += g3*a;
      }
    }
    #pragma unroll
    for (int i = 0; i < 4; ++i){
      int tt = ttb + i;
      const float* ep = A.enc_proj + ((size_t)b*256 + tt)*128 + d0;
      float s = 0.f;
      #pragma unroll
      for (int r = 0; r < 4; ++r){
        v4f v = acc[i][r] + *(const v4f*)&ep[r*4] + *(const v4f*)&decs[d0 + r*4];
        v4f gv = *(const v4f*)&A.g_w[d0 + r*4];
        s += tanhf(v.x)*gv.x + tanhf(v.y)*gv.y + tanhf(v.z)*gv.z + tanhf(v.w)*gv.w;
      }
      s += __shfl_xor(s,1); s += __shfl_xor(s,2); s += __shfl_xor(s,4);
      ebuf[h*4+i] = s;
    }
  }
  if (dg == 0){
    #pragma unroll
    for (int i = 0; i < 8; ++i){
      int tt = tt0 + i;
      float e = ebuf[i] + gb;
      pL[tt] = (tt < il) ? expf(2.0f*e) : 0.0f;
    }
  }
  __syncthreads();
  float pv = pL[tid];
  {
    float v = pv;
    v += __shfl_xor(v,1); v += __shfl_xor(v,2); v += __shfl_xor(v,4);
    v += __shfl_xor(v,8); v += __shfl_xor(v,16); v += __shfl_xor(v,32);
    if ((tid & 63) == 0) red[tid>>6] = v;
  }
  __syncthreads();
  float inv = 1.0f/(red[0]+red[1]+red[2]+red[3]);
  A.out_aws[((size_t)b*256 + t)*256 + tid] = pv*inv;             // block-local + output
  float a0 = 0.f, a1 = 0.f;
  const float* ez = A.enc_z + ((size_t)b*256)*512 + tid;
  #pragma unroll 16
  for (int q = 0; q < 256; ++q){
    float p = pL[q];
    a0 += p*ez[(size_t)q*512];
    a1 += p*ez[(size_t)q*512 + 256];
  }
  float* ac = A.att_c + par*16384 + b*512;
  cst(&ac[tid], a0*inv);                                        // cross-block (sc1)
  cst(&ac[tid + 256], a1*inv);
}

// ---- L0 gates + z0/c0 update. att_c via sc1; z0 via rotating slots:
// write z0(t) -> slot t+1 (sc1, write-through), read z0(t-1) from slot t
// with a NORMAL cached load (address never rewritten => no staleness). ----
__device__ __forceinline__ void l0_body(const Args& A, int par, int blk, int tid,
                                        float* Xl, float* Tg, const float* W4,
                                        const float* zsR, float* zsW){
  const float* acb = A.att_c + par*16384;
  v4f a0={0,0,0,0}, a1={0,0,0,0};
  stage256c(acb, 512, 0, Xl, tid);   gemmK256(W4,        Xl, tid, a0, a1);
  stage256c(acb, 512, 256, Xl, tid); gemmK256(W4 + 4096, Xl, tid, a0, a1);
  int q = tid & 7, b = tid >> 3;
  __syncthreads();
  Tg[b*16 + q]     = hsum(a0);
  Tg[b*16 + q + 8] = hsum(a1);
  __syncthreads();
  if (tid < 128){
    int b2 = tid >> 2, ul = tid & 3;
    int u = blk*4 + ul;
    float gi = Tg[b2*16 + ul*4 + 0];
    float gf = Tg[b2*16 + ul*4 + 1];
    float gg = Tg[b2*16 + ul*4 + 2];
    float go = Tg[b2*16 + ul*4 + 3];
    v4f p1 = cld4(&A.gpre1[par*65536 + b2*2048 + u*4]);          // cross-block (sc1)
    float zo = zsR[b2*512 + u];                                  // rotating, cached
    CWAIT();
    v4f p0 = *(const v4f*)&A.gpre0[b2*2048 + u*4];               // block-local
    v4f bs = *(const v4f*)&A.biasP0[u*4];
    gi += p0.x + p1.x + bs.x; gf += p0.y + p1.y + bs.y;
    gg += p0.z + p1.z + bs.z; go += p0.w + p1.w + bs.w;
    float co = A.c0g[b2*512 + u];                                // block-local
    float c2 = sigf(gf)*co + sigf(gi)*tanhf(gg);
    float h  = sigf(go)*tanhf(c2);
    A.c0g[b2*512 + u] = 0.1f*co + 0.9f*c2;
    cst(&zsW[b2*512 + u], 0.1f*zo + 0.9f*h);                     // fresh slot, sc1
  }
}

// ---- LSTM1 + z1/c1 update. z0 from rotating slot (cached); z1 via sc1 ----
__device__ __forceinline__ void lstm1_body(const Args& A, int par, int m, int tid,
                                           float* Xl, float* Tg, const float* W4,
                                           const float* zs){
  const float* z1rd = A.z1 + (par^1)*16384;
  v4f a0={0,0,0,0}, a1={0,0,0,0};
  stage256 (zs,   512, 0,   Xl, tid); gemmK256(W4,         Xl, tid, a0, a1);
  stage256 (zs,   512, 256, Xl, tid); gemmK256(W4 + 4096,  Xl, tid, a0, a1);
  stage256c(z1rd, 512, 0,   Xl, tid); gemmK256(W4 + 8192,  Xl, tid, a0, a1);
  stage256c(z1rd, 512, 256, Xl, tid); gemmK256(W4 + 12288, Xl, tid, a0, a1);
  int q = tid & 7, b = tid >> 3;
  __syncthreads();
  Tg[b*16 + q]     = hsum(a0);
  Tg[b*16 + q + 8] = hsum(a1);
  __syncthreads();
  if (tid < 128){
    int b2 = tid >> 2, ul = tid & 3;
    int u = m*4 + ul;
    float gi = Tg[b2*16 + ul*4 + 0];
    float gf = Tg[b2*16 + ul*4 + 1];
    float gg = Tg[b2*16 + ul*4 + 2];
    float go = Tg[b2*16 + ul*4 + 3];
    v4f bs = *(const v4f*)&A.biasP1[u*4];
    gi += bs.x; gf += bs.y; gg += bs.z; go += bs.w;
    float co = A.c1g[b2*512 + u];                                // block-local
    float zo = cld(&A.z1[(par^1)*16384 + b2*512 + u]);           // sc1
    float c2 = sigf(gf)*co + sigf(gi)*tanhf(gg);
    float h  = sigf(go)*tanhf(c2);
    A.c1g[b2*512 + u] = 0.1f*co + 0.9f*c2;
    cst(&A.z1[par*16384 + b2*512 + u], 0.1f*zo + 0.9f*h);        // cross-block (sc1)
  }
}

// ---- gpre0 + dec prefetch for next step. z0 from rotating slot (cached) ----
__device__ __forceinline__ void gpre0_body(const Args& A, int blk, int tid,
                                           float* Xl, const float* W4, const float* Wd,
                                           const float* zs){
  v4f a0={0,0,0,0}, a1={0,0,0,0};
  v4f dd4={0,0,0,0};
  int q = tid & 7, b = tid >> 3;
  stage256(zs, 512, 0, Xl, tid);
  gemmK256(W4, Xl, tid, a0, a1);
  if (blk < 32){
    #pragma unroll 8
    for (int i = 0; i < 32; ++i){
      int kl = q*32 + i;
      dd4 += Xl[b*260 + kl] * (*(const v4f*)&Wd[kl*4]);
    }
  }
  stage256(zs, 512, 256, Xl, tid);
  gemmK256(W4 + 4096, Xl, tid, a0, a1);
  if (blk < 32){
    #pragma unroll 8
    for (int i = 0; i < 32; ++i){
      int kl = q*32 + i;
      dd4 += Xl[b*260 + kl] * (*(const v4f*)&Wd[(256+kl)*4]);
    }
    #pragma unroll
    for (int m = 1; m < 8; m <<= 1){
      dd4.x += __shfl_xor(dd4.x, m); dd4.y += __shfl_xor(dd4.y, m);
      dd4.z += __shfl_xor(dd4.z, m); dd4.w += __shfl_xor(dd4.w, m);
    }
    if (q == 0){
      float* dp = &A.dec[b*128 + blk*4];                         // cross-block (sc1)
      cst(&dp[0], dd4.x); cst(&dp[1], dd4.y);
      cst(&dp[2], dd4.z); cst(&dp[3], dd4.w);
    }
  }
  float* dst = A.gpre0 + b*2048 + blk*16;                        // block-local
  dst[q]     = hsum(a0);
  dst[q + 8] = hsum(a1);
}

// ---- grid barrier: fence-free (cross-block data uses sc1 accesses).
// __syncthreads drains vmcnt before s_barrier, so by the time thread 0
// publishes the arrive flag, all coherent data stores have completed. ----
#define COLL 255
__device__ __forceinline__ void gsync(unsigned* bars, unsigned idx){
  unsigned* go = bars + 384;
  asm volatile("" ::: "memory");
  __syncthreads();
  if (threadIdx.x == 0)
    __hip_atomic_store(&bars[blockIdx.x], idx, __ATOMIC_RELAXED, __HIP_MEMORY_SCOPE_AGENT);
  if (blockIdx.x == COLL){
    while (__hip_atomic_load(&bars[threadIdx.x], __ATOMIC_RELAXED, __HIP_MEMORY_SCOPE_AGENT) < idx)
      __builtin_amdgcn_s_sleep(1);
    __syncthreads();
    if (threadIdx.x == 0)
      __hip_atomic_store(go, idx, __ATOMIC_RELAXED, __HIP_MEMORY_SCOPE_AGENT);
  }
  if (threadIdx.x == 0){
    while (__hip_atomic_load(go, __ATOMIC_RELAXED, __HIP_MEMORY_SCOPE_AGENT) < idx)
      __builtin_amdgcn_s_sleep(1);
  }
  __syncthreads();
  asm volatile("" ::: "memory");
}

// ---------------- persistent loop (grid=256, 1 block/CU by LDS) ----------------
// roles: blk 0-31: att (A) + L0 (B) + gpre0/dec (C)
//        blk 32-127: L0 (B) + gpre0 (C)
//        blk 128-191: gpre1(t+1) (A) + LSTM1 (C)
//        blk 192-232: out(t-1) (A) + LSTM1 (C)
//        blk 233-255: LSTM1 (C)
__global__ void __launch_bounds__(256, 1) k_loop(Args A){
  extern __shared__ float L[];
  float* Xl = L + L_XL;
  float* Tg = L + L_TG;
  float* W4 = L + L_W4;
  float* WX = L + L_WX;
  int blk = blockIdx.x, tid = threadIdx.x;

  // ---- one-time LDS weight residency ----
  if (blk < 128){
    const float* src = A.W0pack + (size_t)blk*16384;
    for (int i = tid*4; i < 16384; i += 1024) *(v4f*)&W4[i] = *(const v4f*)&src[i];
    if (blk < 32){
      const float* sd = A.Wdpack + (size_t)blk*2048;
      for (int i = tid; i < 2048; i += 256) WX[i] = sd[i];
      for (int i = tid; i < 3968; i += 256) L[L_GS + i] = A.G[i];
    }
  } else {
    const float* src = A.W1pack + (size_t)(blk-128)*16384;
    for (int i = tid*4; i < 16384; i += 1024) *(v4f*)&W4[i] = *(const v4f*)&src[i];
    if (blk < 192){
      const float* sp = A.Wp1pack + (size_t)(blk-128)*8192;
      for (int i = tid*4; i < 8192; i += 1024) *(v4f*)&WX[i] = *(const v4f*)&sp[i];
    } else if (blk < 233){
      const float* sf = A.WFpack + (size_t)(blk-192)*2048;
      for (int i = tid; i < 2048; i += 256) WX[i] = sf[i];
    }
  }
  __syncthreads();

  unsigned sidx = 0;

  // bootstrap gpre1(0) (parity 0)
  if (blk >= 128 && blk < 192) gp1_body(A, 0, blk-128, tid, Xl, WX);
  gsync(A.bars, ++sidx);

  for (int t = 0; t < LSEQ; ++t){
    int par = t & 1;
    const float* zsR = zslot(A, t);       // z0(t-1)
    float*       zsW = zslot(A, t+1);     // z0(t)
    // ---- phase A: attention | gpre1(t+1) | out(t-1) ----
    if (blk < 32){
      att_body(A, t, blk, tid, L);
    } else if (blk >= 128 && blk < 192){
      if (t < 255) gp1_body(A, t+1, blk-128, tid, Xl, WX);
    } else if (blk >= 192 && blk < 233){
      if (t > 0) out_phase(A, A.z1 + (par^1)*16384, A.att_c + (par^1)*16384,
                           t-1, blk-192, tid, Xl, Tg, WX);
    }
    gsync(A.bars, ++sidx);
    // ---- phase B: L0 gates + z0 update (writes slot t+1) ----
    if (blk < 128) l0_body(A, par, blk, tid, Xl, Tg, W4, zsR, zsW);
    gsync(A.bars, ++sidx);
    // ---- phase C: LSTM1 | gpre0/dec prefetch (read slot t+1, cached) ----
    if (blk >= 128) lstm1_body(A, par, blk-128, tid, Xl, Tg, W4, zsW);
    else if (t < 255) gpre0_body(A, blk, tid, Xl, W4 + 8192, WX, zsW);
    gsync(A.bars, ++sidx);
  }
  // ---- tail: out(255) (parity 1) ----
  if (blk >= 192 && blk < 233)
    out_phase(A, A.z1 + 16384, A.att_c + 16384, 255, blk-192, tid, Xl, Tg, WX);
}

// ---------------- postnet conv (kernel=5, pad=2) as tiled GEMM ----------------
__global__ void __launch_bounds__(256) k_conv(const float* __restrict__ in,
                       const float* __restrict__ Wt,
                       const float* __restrict__ sc, const float* __restrict__ sh,
                       float* __restrict__ out0, const float* __restrict__ before,
                       float* __restrict__ after, int C, int N, int mode)
{
  __shared__ __align__(16) float As[16][64];
  __shared__ __align__(16) float Bs[16][64];
  int bx = blockIdx.x;
  int b = bx >> 2, l0 = (bx & 3)*64;
  int n0 = blockIdx.y*64;
  int tid = threadIdx.x, tx = tid & 15, ty = tid >> 4;
  float acc[4][4];
  #pragma unroll
  for (int i = 0; i < 4; ++i)
    #pragma unroll
    for (int j = 0; j < 4; ++j) acc[i][j] = 0.f;
  for (int k = 0; k < 5; ++k){
    int shift = k - 2;
    for (int c0 = 0; c0 < C; c0 += 16){
      #pragma unroll
      for (int i = 0; i < 4; ++i){
        int e = tid + i*256; int cc = e >> 6, ll = e & 63;
        int l = l0 + ll + shift;
        As[cc][ll] = ((unsigned)l < 256u) ? in[((size_t)(b*C + c0+cc))*256 + l] : 0.f;
        int n = n0 + ll;
        Bs[cc][ll] = (n < N) ? Wt[((size_t)k*C + c0+cc)*(size_t)N + n] : 0.f;
      }
      __syncthreads();
      #pragma unroll
      for (int cc = 0; cc < 16; ++cc){
        const float4 av = *reinterpret_cast<const float4*>(&As[cc][ty<<2]);
        const float4 bv = *reinterpret_cast<const float4*>(&Bs[cc][tx<<2]);
        acc[0][0]+=av.x*bv.x; acc[0][1]+=av.x*bv.y; acc[0][2]+=av.x*bv.z; acc[0][3]+=av.x*bv.w;
        acc[1][0]+=av.y*bv.x; acc[1][1]+=av.y*bv.y; acc[1][2]+=av.y*bv.z; acc[1][3]+=av.y*bv.w;
        acc[2][0]+=av.z*bv.x; acc[2][1]+=av.z*bv.y; acc[2][2]+=av.z*bv.z; acc[2][3]+=av.z*bv.w;
        acc[3][0]+=av.w*bv.x; acc[3][1]+=av.w*bv.y; acc[3][2]+=av.w*bv.z; acc[3][3]+=av.w*bv.w;
      }
      __syncthreads();
    }
  }
  #pragma unroll
  for (int i = 0; i < 4; ++i){
    int l = l0 + (ty<<2) + i;
    #pragma unroll
    for (int j = 0; j < 4; ++j){
      int n = n0 + (tx<<2) + j;
      if (n < N){
        float v = sc[n]*acc[i][j] + sh[n];
        if (mode == 0){
          out0[((size_t)(b*N + n))*256 + l] = tanhf(v);
        } else {
          size_t ob2 = ((size_t)b*256 + l)*80 + n;
          after[ob2] = before[ob2] + v;
        }
      }
    }
  }
}

extern "C" void kernel_launch(void* const* d_in, const int* in_sizes, int n_in,
                              void* d_out, int out_size, void* d_ws, size_t ws_size,
                              hipStream_t stream) {
  Args A;
  A.enc_z = (const float*)d_in[0];  A.ys = (const float*)d_in[1];
  A.ilens = (const int*)d_in[3];
  A.W_enc = (const float*)d_in[4];  A.b_enc = (const float*)d_in[5];
  A.W_dec = (const float*)d_in[6];  A.loc_kernel = (const float*)d_in[7];
  A.W_att = (const float*)d_in[8];  A.g_w = (const float*)d_in[9];  A.g_b = (const float*)d_in[10];
  A.Wp0 = (const float*)d_in[11];   A.bp0 = (const float*)d_in[12];
  A.Wp1 = (const float*)d_in[13];   A.bp1 = (const float*)d_in[14];
  A.Wih0 = (const float*)d_in[15];  A.Whh0 = (const float*)d_in[16];
  A.bih0 = (const float*)d_in[17];  A.bhh0 = (const float*)d_in[18];
  A.Wih1 = (const float*)d_in[19];  A.Whh1 = (const float*)d_in[20];
  A.bih1 = (const float*)d_in[21];  A.bhh1 = (const float*)d_in[22];
  A.Wf = (const float*)d_in[23];    A.bf = (const float*)d_in[24];
  A.Wq = (const float*)d_in[25];    A.bq = (const float*)d_in[26];
  A.pk0 = (const float*)d_in[27];   A.pb0 = (const float*)d_in[28];
  A.bg0 = (const float*)d_in[29];   A.bb0 = (const float*)d_in[30];
  A.pk1 = (const float*)d_in[31];   A.pb1 = (const float*)d_in[32];
  A.bg1 = (const float*)d_in[33];   A.bb1 = (const float*)d_in[34];
  A.pk2 = (const float*)d_in[35];   A.pb2 = (const float*)d_in[36];
  A.bg2 = (const float*)d_in[37];   A.bb2 = (const float*)d_in[38];

  float* ws = (float*)d_ws;
  size_t off = 0;
  auto alloc = [&](size_t n){ float* p = ws + off; off += n; return p; };
  A.enc_proj   = alloc(1048576);
  A.pre_tmp    = alloc(2097152);
  A.pre_all    = alloc(2097152);
  A.G          = alloc(3968);
  A.dec        = alloc(4096);
  A.att_c      = alloc(32768);
  A.z0         = alloc(16384);
  A.z1         = alloc(32768);
  A.c0g        = alloc(16384);
  A.c1g        = alloc(16384);
  A.gpre0      = alloc(65536);
  A.gpre1      = alloc(131072);
  A.biasP0     = alloc(2048);
  A.biasP1     = alloc(2048);
  A.before_t   = alloc(655360);
  A.h0         = alloc(4194304);
  A.h1         = alloc(4194304);
  A.Wt0        = alloc(204800);
  A.Wt1        = alloc(1310720);
  A.Wt2        = alloc(204800);
  A.s0 = alloc(512); A.t0s = alloc(512);
  A.s1 = alloc(512); A.t1s = alloc(512);
  A.s2 = alloc(128); A.t2s = alloc(128);
  A.bars = (unsigned*)alloc(512);
  // weight packs alias the postnet activation buffers (consumed by k_loop
  // before postnet runs; k_init refills them at the start of every replay)
  A.W0pack  = A.h0;                       // 128*16384 = 2097152
  A.W1pack  = A.h0 + 2097152;             // 2097152
  A.Wp1pack = A.h1;                       // 64*8192 = 524288
  A.WFpack  = A.h1 + 524288;              // 41*2048 = 83968
  A.Wdpack  = A.h1 + 524288 + 83968;      // 32*2048 = 65536 (packs end 673792)
  // rotating z0 slots: 257 x 16384 floats, never-reused addresses.
  //   slots 0..213  -> h1 tail  [673792 .. 673792+3506176=4179968) < 4194304
  //   slots 214..256 -> pre_tmp [0 .. 704512) (dead after k_pre1)
  // conv-2 overwrites h1 only after k_loop retires.
  A.z0rA = A.h1 + 673792;
  A.z0rB = A.pre_tmp;

  float* out = (float*)d_out;
  A.out_after  = out;
  A.out_before = out + 655360;
  A.out_logits = out + 1310720;
  A.out_aws    = out + 1318912;

  hipFuncSetAttribute((const void*)k_loop,
                      hipFuncAttributeMaxDynamicSharedMemorySize, DYN_L);

  k_init<<<dim3(1024), dim3(256), 0, stream>>>(A);
  k_encproj<<<dim3(256), dim3(256), 0, stream>>>(A);
  k_pre0<<<dim3(256), dim3(256), 0, stream>>>(A);
  k_pre1<<<dim3(256), dim3(256), 0, stream>>>(A);

  // Plain launch: grid=256 with 130.6 KiB dynamic LDS forces 1 block/CU on
  // 256 CUs -> all blocks co-resident, so the flag-array grid barrier is safe.
  k_loop<<<dim3(256), dim3(256), DYN_L, stream>>>(A);

  k_conv<<<dim3(128,8), dim3(256), 0, stream>>>(A.before_t, A.Wt0, A.s0, A.t0s, A.h0, nullptr, nullptr, 80, 512, 0);
  k_conv<<<dim3(128,8), dim3(256), 0, stream>>>(A.h0, A.Wt1, A.s1, A.t1s, A.h1, nullptr, nullptr, 512, 512, 0);
  k_conv<<<dim3(128,2), dim3(256), 0, stream>>>(A.h1, A.Wt2, A.s2, A.t2s, nullptr, A.out_before, A.out_after, 512, 80, 1);
}

// Round 11
// 43459.369 us; speedup vs baseline: 2.1145x; 1.0241x over previous
//
#include <hip/hip_runtime.h>
#include <cstdint>

#define LSEQ 256
#define BN_INV 0.99999500003750f

typedef float v4f __attribute__((ext_vector_type(4)));

#define DYN_L 133760   // 33440 floats: Xl 8320 | Tg 544 | W4 16384 | WX 2048/8192 | attn region

// LDS float offsets for the persistent kernel
#define L_XL   0
#define L_TG   8320
#define L_W4   8864      // 16384 floats: [Wih|Whh] image
#define L_WX   25248     // Wd (2048) | Wp1s (8192) | WFs (2048)
#define L_GS   27296     // 3968 (attn blocks only; after their 2048-float Wd)
#define L_AW   31264     // 288
#define L_PL   31552     // 256
#define L_DEC  31808     // 128
#define L_RED  31936     // 4  -> end 31940 (< 33440)

// z0 rotation: slot s at z0rA[s] for s<214, else z0rB[s-214]. 257 slots, each
// 16384 floats. Addresses are NEVER reused => consumers may use plain cached
// loads with no stale-line hazard; producers write-through with sc1.
#define ZSLOT_A 214

struct Args {
  const float *enc_z, *ys;
  const int* ilens;
  const float *W_enc, *b_enc, *W_dec, *loc_kernel, *W_att, *g_w, *g_b;
  const float *Wp0, *bp0, *Wp1, *bp1;
  const float *Wih0, *Whh0, *bih0, *bhh0, *Wih1, *Whh1, *bih1, *bhh1;
  const float *Wf, *bf, *Wq, *bq;
  const float *pk0,*pb0,*bg0,*bb0,*pk1,*pb1,*bg1,*bb1,*pk2,*pb2,*bg2,*bb2;
  float *enc_proj, *pre_tmp, *pre_all, *G, *dec, *att_c;
  float *z0, *z1, *c0g, *c1g, *gpre0, *gpre1, *biasP0, *biasP1;
  float *before_t, *h0, *h1, *Wt0, *Wt1, *Wt2, *s0, *t0s, *s1, *t1s, *s2, *t2s;
  float *W0pack, *W1pack, *Wp1pack, *WFpack, *Wdpack;
  float *z0rA, *z0rB;   // rotating z0 slots (h1 tail / dead pre_tmp)
  float *out_after, *out_before, *out_logits, *out_aws;
  unsigned *bars;   // [0..255] arrive flags, [384+g*32] go flags (8 lines)
};

__device__ __forceinline__ float sigf(float x){ return 1.0f/(1.0f+expf(-x)); }
__device__ __forceinline__ float hsum(const v4f& v){ return v.x+v.y+v.z+v.w; }

__device__ __forceinline__ float* zslot(const Args& A, int s){
  return (s < ZSLOT_A) ? A.z0rA + (size_t)s*16384
                       : A.z0rB + (size_t)(s - ZSLOT_A)*16384;
}

// ---- coherent (device-scope) accessors for cross-block buffers ----
__device__ __forceinline__ float cld(const float* p){
  return __hip_atomic_load(p, __ATOMIC_RELAXED, __HIP_MEMORY_SCOPE_AGENT);
}
__device__ __forceinline__ void cst(float* p, float v){
  __hip_atomic_store(p, v, __ATOMIC_RELAXED, __HIP_MEMORY_SCOPE_AGENT);
}
// wide pipelined coherent load (bypasses stale caches; drain with CWAIT)
__device__ __forceinline__ v4f cld4(const float* p){
  v4f v;
  asm volatile("global_load_dwordx4 %0, %1, off sc0 sc1" : "=v"(v) : "v"(p));
  return v;
}
#define CWAIT() do { asm volatile("s_waitcnt vmcnt(0)" ::: "memory"); \
                     __builtin_amdgcn_sched_barrier(0); } while(0)

// ---------------- init: precomputes + per-block weight packs ----------------
__global__ void k_init(Args A){
  int tid0 = blockIdx.x*blockDim.x + threadIdx.x;
  int stride = gridDim.x*blockDim.x;
  for (int i = tid0; i < 1024; i += stride) A.bars[i] = 0u;
  for (int i = tid0; i < 16384; i += stride) A.z0rA[i] = 0.f;   // rot slot 0
  for (int i = tid0; i < 31*128; i += stride){
    int k = i >> 7, d = i & 127;
    float s = 0.f;
    for (int c = 0; c < 32; ++c) s += A.W_att[c*128+d]*A.loc_kernel[c*31+k];
    A.G[i] = s;
  }
  for (int i = tid0; i < 2048; i += stride){
    int u = i & 511, g = i >> 9;
    A.biasP0[u*4+g] = A.bih0[i]+A.bhh0[i];
    A.biasP1[u*4+g] = A.bih1[i]+A.bhh1[i];
  }
  for (int i = tid0; i < 16384; i += stride){ A.z0[i]=0.f; A.c0g[i]=0.f; A.c1g[i]=0.f; }
  for (int i = tid0; i < 32768; i += stride) A.z1[i]=0.f;
  for (int i = tid0; i < 65536; i += stride) A.gpre0[i]=0.f;
  for (int i = tid0; i < 4096; i += stride) A.dec[i]=0.f;
  for (int i = tid0; i < 512; i += stride){
    float s = A.bg0[i]*BN_INV; A.s0[i]=s; A.t0s[i]=s*A.pb0[i]+A.bb0[i];
    float u = A.bg1[i]*BN_INV; A.s1[i]=u; A.t1s[i]=u*A.pb1[i]+A.bb1[i];
  }
  for (int i = tid0; i < 80; i += stride){
    float s = A.bg2[i]*BN_INV; A.s2[i]=s; A.t2s[i]=s*A.pb2[i]+A.bb2[i];
  }
  for (int i = tid0; i < 5*80*512; i += stride){
    int k = i/(80*512); int r = i - k*(80*512); int c = r>>9, n = r&511;
    A.Wt0[i] = A.pk0[(n*80+c)*5+k];
  }
  for (int i = tid0; i < 5*512*512; i += stride){
    int k = i/(512*512); int r = i - k*(512*512); int c = r>>9, n = r&511;
    A.Wt1[i] = A.pk1[(n*512+c)*5+k];
  }
  for (int i = tid0; i < 5*512*80; i += stride){
    int k = i/(512*80); int r = i - k*(512*80); int c = r/80, n = r - c*80;
    A.Wt2[i] = A.pk2[(n*512+c)*5+k];
  }
  // ---- per-block weight packs (LDS image order => coalesced reload) ----
  for (int i = tid0; i < 128*16384; i += stride){
    int blk = i >> 14, idx = i & 16383;
    int kq = idx >> 6, rem = idx & 63, p = rem >> 2, kl = rem & 3;
    int k = kq*4 + kl;
    int gcol = (p & 3)*512 + blk*4 + (p >> 2);
    A.W0pack[i] = (k < 512) ? A.Wih0[(size_t)k*2048 + gcol]
                            : A.Whh0[(size_t)(k-512)*2048 + gcol];
  }
  for (int i = tid0; i < 128*16384; i += stride){
    int blk = i >> 14, idx = i & 16383;
    int kq = idx >> 6, rem = idx & 63, p = rem >> 2, kl = rem & 3;
    int k = kq*4 + kl;
    int gcol = (p & 3)*512 + blk*4 + (p >> 2);
    A.W1pack[i] = (k < 512) ? A.Wih1[(size_t)k*2048 + gcol]
                            : A.Whh1[(size_t)(k-512)*2048 + gcol];
  }
  for (int i = tid0; i < 64*8192; i += stride){
    int m = i >> 13, idx = i & 8191;
    int kq = idx >> 7, rem = idx & 127, p = rem >> 2, kl = rem & 3;
    int k = kq*4 + kl;
    int gcol = (p & 3)*512 + m*8 + (p >> 2);
    A.Wp1pack[i] = A.Wih0[(size_t)(512+k)*2048 + gcol];
  }
  for (int i = tid0; i < 41*2048; i += stride){
    int blk = i >> 11, k2 = i & 2047;
    int k = k2 >> 1, e = k2 & 1, c = blk*2 + e;
    A.WFpack[i] = (c < 80) ? A.Wf[(size_t)k*80 + c] : A.Wq[k];
  }
  for (int i = tid0; i < 32*2048; i += stride){
    int blk = i >> 11, j = i & 2047;
    int k = j >> 2, c = j & 3;
    A.Wdpack[i] = A.W_dec[(size_t)k*128 + blk*4 + c];
  }
}

// ---------------- enc_proj ----------------
__global__ void __launch_bounds__(256) k_encproj(Args A){
  __shared__ __align__(16) float As[32][128];
  int m0 = blockIdx.x*32;
  int tid = threadIdx.x;
  int d = tid & 127, half = tid >> 7;
  float acc[16];
  #pragma unroll
  for (int r = 0; r < 16; ++r) acc[r] = 0.f;
  for (int j0 = 0; j0 < 512; j0 += 128){
    for (int i = 0; i < 16; ++i){
      int e = tid + i*256; int r = e >> 7, j = e & 127;
      As[r][j] = A.enc_z[(size_t)(m0+r)*512 + j0 + j];
    }
    __syncthreads();
    for (int j = 0; j < 128; ++j){
      float w = A.W_enc[(size_t)(j0+j)*128 + d];
      #pragma unroll
      for (int r = 0; r < 16; ++r) acc[r] += As[half*16+r][j]*w;
    }
    __syncthreads();
  }
  float be = A.b_enc[d];
  for (int r = 0; r < 16; ++r)
    A.enc_proj[(size_t)(m0+half*16+r)*128 + d] = acc[r] + be;
}

// ---------------- prenet ----------------
__global__ void __launch_bounds__(256) k_pre0(Args A){
  __shared__ float As[32][80];
  int m0 = blockIdx.x*32, tid = threadIdx.x;
  for (int e = tid; e < 2560; e += 256){
    int r = e/80, o = e - r*80;
    int row = m0+r; int l = row & 255, b = row >> 8;
    As[r][o] = (l==0) ? 0.f : A.ys[((size_t)b*256 + (l-1))*80 + o];
  }
  __syncthreads();
  float acc[32];
  #pragma unroll
  for (int r = 0; r < 32; ++r) acc[r] = 0.f;
  for (int o = 0; o < 80; ++o){
    float w = A.Wp0[o*256 + tid];
    #pragma unroll
    for (int r = 0; r < 32; ++r) acc[r] += As[r][o]*w;
  }
  float bb = A.bp0[tid];
  for (int r = 0; r < 32; ++r){
    float v = acc[r]+bb;
    A.pre_tmp[(size_t)(m0+r)*256 + tid] = v>0.f?v:0.f;
  }
}

__global__ void __launch_bounds__(256) k_pre1(Args A){
  __shared__ float As[32][256];
  int m0 = blockIdx.x*32, tid = threadIdx.x;
  for (int e = tid; e < 8192; e += 256){
    int r = e >> 8, j = e & 255;
    As[r][j] = A.pre_tmp[(size_t)(m0+r)*256 + j];
  }
  __syncthreads();
  float acc[32];
  #pragma unroll
  for (int r = 0; r < 32; ++r) acc[r] = 0.f;
  for (int j = 0; j < 256; ++j){
    float w = A.Wp1[j*256 + tid];
    #pragma unroll
    for (int r = 0; r < 32; ++r) acc[r] += As[r][j]*w;
  }
  float bb = A.bp1[tid];
  for (int r = 0; r < 32; ++r){
    float v = acc[r]+bb;
    A.pre_all[(size_t)(m0+r)*256 + tid] = v>0.f?v:0.f;
  }
}

// ---- stage 32 rows x 256 floats into LDS (pitch 260), normal cached loads ----
__device__ __forceinline__ void stage256(const float* base, int rowstride, int koff,
                                         float* Xl, int tid){
  v4f r0,r1,r2,r3,r4,r5,r6,r7;
  #define LDX(i,dst) { int f=tid+((i)<<8); int b=f>>6; int jq=f&63; \
      dst = *(const v4f*)(base + (size_t)b*rowstride + koff + jq*4); }
  LDX(0,r0) LDX(1,r1) LDX(2,r2) LDX(3,r3) LDX(4,r4) LDX(5,r5) LDX(6,r6) LDX(7,r7)
  #undef LDX
  __syncthreads();
  #define STX(i,src) { int f=tid+((i)<<8); int b=f>>6; int jq=f&63; \
      *(v4f*)&Xl[b*260 + jq*4] = src; }
  STX(0,r0) STX(1,r1) STX(2,r2) STX(3,r3) STX(4,r4) STX(5,r5) STX(6,r6) STX(7,r7)
  #undef STX
  __syncthreads();
}

// ---- coherent variant: pipelined dwordx4 sc0 sc1 loads + one explicit drain ----
__device__ __forceinline__ void stage256c(const float* base, int rowstride, int koff,
                                          float* Xl, int tid){
  v4f r0,r1,r2,r3,r4,r5,r6,r7;
  #define LDX(i,dst) { int f=tid+((i)<<8); int b=f>>6; int jq=f&63; \
      dst = cld4(base + (size_t)b*rowstride + koff + jq*4); }
  LDX(0,r0) LDX(1,r1) LDX(2,r2) LDX(3,r3) LDX(4,r4) LDX(5,r5) LDX(6,r6) LDX(7,r7)
  #undef LDX
  CWAIT();
  __syncthreads();
  #define STX(i,src) { int f=tid+((i)<<8); int b=f>>6; int jq=f&63; \
      *(v4f*)&Xl[b*260 + jq*4] = src; }
  STX(0,r0) STX(1,r1) STX(2,r2) STX(3,r3) STX(4,r4) STX(5,r5) STX(6,r6) STX(7,r7)
  #undef STX
  __syncthreads();
}

// ---- K=256 chunk gemm ----
__device__ __forceinline__ void gemmK256(const float* __restrict__ W4,
                                         const float* __restrict__ Xl,
                                         int tid, v4f& a0, v4f& a1){
  const int q = tid & 7, b = tid >> 3;
  const float* xr = Xl + b*260;
  #pragma unroll 8
  for (int jq = 0; jq < 64; ++jq){
    v4f xv = *(const v4f*)&xr[jq*4];
    v4f w0 = *(const v4f*)&W4[jq*64 + q*4];
    v4f w1 = *(const v4f*)&W4[jq*64 + (q+8)*4];
    a0 += xv*w0; a1 += xv*w1;
  }
}

// ---- out(tt): 2 cols of [Wf|Wq], K=1024 over [z1; att_c] ----
__device__ __forceinline__ void out_phase(const Args& A, const float* z1b, const float* acb,
                                          int tt, int ob, int tid, float* Xl, float* Tg,
                                          const float* WF){
  int b = tid >> 3, sub = tid & 7;
  float acc0 = 0.f, acc1 = 0.f;
  for (int pass = 0; pass < 4; ++pass){
    const float* src = (pass < 2) ? z1b : acb;
    stage256c(src, 512, (pass & 1)*256, Xl, tid);
    int kbase = pass*256;
    #pragma unroll 4
    for (int i = 0; i < 32; ++i){
      int k = sub + 8*i;
      float x = Xl[b*260 + k];
      acc0 += x*WF[(kbase+k)*2 + 0];
      acc1 += x*WF[(kbase+k)*2 + 1];
    }
    __syncthreads();
  }
  Tg[(b*8+sub)*2+0] = acc0; Tg[(b*8+sub)*2+1] = acc1;
  __syncthreads();
  if (tid < 64){
    int b2 = tid >> 1, e = tid & 1, cg = ob*2 + e;
    float v = (cg < 80) ? A.bf[cg] : A.bq[0];
    for (int s = 0; s < 8; ++s) v += Tg[(b2*8+s)*2 + e];
    if (cg < 80){
      A.out_before[((size_t)b2*256 + tt)*80 + cg] = v;
      A.before_t[((size_t)b2*80 + cg)*256 + tt] = v;
    } else if (cg == 80){
      A.out_logits[(size_t)b2*256 + tt] = v;
    }
  }
}

// ---- gpre1(tp): one block = 8 units (32 gate-cols), K=256 over pre(tp) ----
__device__ __forceinline__ void gp1_body(const Args& A, int tp, int m2, int tid,
                                         float* Xl, const float* Wp4){
  stage256(A.pre_all + (size_t)tp*256, 65536, 0, Xl, tid);   // pre_all: read-only, cached
  int q = tid & 7, b = tid >> 3;
  v4f a0={0,0,0,0}, a1={0,0,0,0}, a2={0,0,0,0}, a3={0,0,0,0};
  const float* xr = Xl + b*260;
  #pragma unroll 8
  for (int jq = 0; jq < 64; ++jq){
    v4f xv = *(const v4f*)&xr[jq*4];
    a0 += xv * (*(const v4f*)&Wp4[jq*128 + q*4]);
    a1 += xv * (*(const v4f*)&Wp4[jq*128 + (q+8)*4]);
    a2 += xv * (*(const v4f*)&Wp4[jq*128 + (q+16)*4]);
    a3 += xv * (*(const v4f*)&Wp4[jq*128 + (q+24)*4]);
  }
  float* dst = A.gpre1 + (tp&1)*65536 + b*2048 + m2*32;
  cst(&dst[q],      hsum(a0));
  cst(&dst[q + 8],  hsum(a1));
  cst(&dst[q + 16], hsum(a2));
  cst(&dst[q + 24], hsum(a3));
}

// ---- attention body (per-b block), Gs already LDS-resident ----
__device__ __forceinline__ void att_body(const Args& A, int t, int b, int tid, float* L){
  const float* Gs = L + L_GS;
  float* awin = L + L_AW;
  float* pL   = L + L_PL;
  float* decs = L + L_DEC;
  float* red  = L + L_RED;
  int par = t & 1;
  int il = A.ilens[b];
  for (int i = tid; i < 288; i += 256){
    int tt = i - 15;
    float v = 0.f;
    if ((unsigned)tt < 256u)
      v = t ? A.out_aws[((size_t)b*256 + (t-1))*256 + tt]       // block-local, cached
            : ((tt < il) ? 1.0f/(float)il : 0.f);
    awin[i] = v;
  }
  if (tid < 128) decs[tid] = cld(&A.dec[b*128 + tid]);          // cross-block
  __syncthreads();
  float gb = A.g_b[0];
  int dg = tid & 7, ttg = tid >> 3;
  int d0 = dg*16, tt0 = ttg*8;
  float ebuf[8];
  #pragma unroll
  for (int h = 0; h < 2; ++h){
    int ttb = tt0 + h*4;
    float aw[34];
    #pragma unroll
    for (int i = 0; i < 34; ++i) aw[i] = awin[ttb + i];
    v4f acc[4][4];
    #pragma unroll
    for (int i = 0; i < 4; ++i)
      #pragma unroll
      for (int r = 0; r < 4; ++r) acc[i][r] = (v4f){0.f,0.f,0.f,0.f};
    #pragma unroll
    for (int k = 0; k < 31; ++k){
      const float* gp = &Gs[k*128 + d0];
      v4f g0 = *(const v4f*)&gp[0],  g1 = *(const v4f*)&gp[4];
      v4f g2 = *(const v4f*)&gp[8],  g3 = *(const v4f*)&gp[12];
      #pragma unroll
      for (int i = 0; i < 4; ++i){
        float a = aw[i + k];
        acc[i][0] += g0*a; acc[i][1] += g1*a; acc[i][2] += g2*a; acc[i][3] += g3*a;
      }
    }
    #pragma unroll
    for (int i = 0; i < 4; ++i){
      int tt = ttb + i;
      const float* ep = A.enc_proj + ((size_t)b*256 + tt)*128 + d0;
      float s = 0.f;
      #pragma unroll
      for (int r = 0; r < 4; ++r){
        v4f v = acc[i][r] + *(const v4f*)&ep[r*4] + *(const v4f*)&decs[d0 + r*4];
        v4f gv = *(const v4f*)&A.g_w[d0 + r*4];
        s += tanhf(v.x)*gv.x + tanhf(v.y)*gv.y + tanhf(v.z)*gv.z + tanhf(v.w)*gv.w;
      }
      s += __shfl_xor(s,1); s += __shfl_xor(s,2); s += __shfl_xor(s,4);
      ebuf[h*4+i] = s;
    }
  }
  if (dg == 0){
    #pragma unroll
    for (int i = 0; i < 8; ++i){
      int tt = tt0 + i;
      float e = ebuf[i] + gb;
      pL[tt] = (tt < il) ? expf(2.0f*e) : 0.0f;
    }
  }
  __syncthreads();
  float pv = pL[tid];
  {
    float v = pv;
    v += __shfl_xor(v,1); v += __shfl_xor(v,2); v += __shfl_xor(v,4);
    v += __shfl_xor(v,8); v += __shfl_xor(v,16); v += __shfl_xor(v,32);
    if ((tid & 63) == 0) red[tid>>6] = v;
  }
  __syncthreads();
  float inv = 1.0f/(red[0]+red[1]+red[2]+red[3]);
  A.out_aws[((size_t)b*256 + t)*256 + tid] = pv*inv;             // block-local + output
  float a0 = 0.f, a1 = 0.f;
  const float* ez = A.enc_z + ((size_t)b*256)*512 + tid;
  #pragma unroll 16
  for (int q = 0; q < 256; ++q){
    float p = pL[q];
    a0 += p*ez[(size_t)q*512];
    a1 += p*ez[(size_t)q*512 + 256];
  }
  float* ac = A.att_c + par*16384 + b*512;
  cst(&ac[tid], a0*inv);                                        // cross-block (sc1)
  cst(&ac[tid + 256], a1*inv);
}

// ---- L0 gates + z0/c0 update. att_c via sc1; z0 via rotating slots:
// write z0(t) -> slot t+1 (sc1, write-through), read z0(t-1) from slot t
// with a NORMAL cached load (address never rewritten => no staleness). ----
__device__ __forceinline__ void l0_body(const Args& A, int par, int blk, int tid,
                                        float* Xl, float* Tg, const float* W4,
                                        const float* zsR, float* zsW){
  const float* acb = A.att_c + par*16384;
  v4f a0={0,0,0,0}, a1={0,0,0,0};
  stage256c(acb, 512, 0, Xl, tid);   gemmK256(W4,        Xl, tid, a0, a1);
  stage256c(acb, 512, 256, Xl, tid); gemmK256(W4 + 4096, Xl, tid, a0, a1);
  int q = tid & 7, b = tid >> 3;
  __syncthreads();
  Tg[b*16 + q]     = hsum(a0);
  Tg[b*16 + q + 8] = hsum(a1);
  __syncthreads();
  if (tid < 128){
    int b2 = tid >> 2, ul = tid & 3;
    int u = blk*4 + ul;
    float gi = Tg[b2*16 + ul*4 + 0];
    float gf = Tg[b2*16 + ul*4 + 1];
    float gg = Tg[b2*16 + ul*4 + 2];
    float go = Tg[b2*16 + ul*4 + 3];
    v4f p1 = cld4(&A.gpre1[par*65536 + b2*2048 + u*4]);          // cross-block (sc1)
    float zo = zsR[b2*512 + u];                                  // rotating, cached
    CWAIT();
    v4f p0 = *(const v4f*)&A.gpre0[b2*2048 + u*4];               // block-local
    v4f bs = *(const v4f*)&A.biasP0[u*4];
    gi += p0.x + p1.x + bs.x; gf += p0.y + p1.y + bs.y;
    gg += p0.z + p1.z + bs.z; go += p0.w + p1.w + bs.w;
    float co = A.c0g[b2*512 + u];                                // block-local
    float c2 = sigf(gf)*co + sigf(gi)*tanhf(gg);
    float h  = sigf(go)*tanhf(c2);
    A.c0g[b2*512 + u] = 0.1f*co + 0.9f*c2;
    cst(&zsW[b2*512 + u], 0.1f*zo + 0.9f*h);                     // fresh slot, sc1
  }
}

// ---- LSTM1 part C: z0 half (rotating slot, cached) + epilogue.
// a0/a1 already hold the z1(t-1) half computed in phase B. ----
__device__ __forceinline__ void lstm1_partC(const Args& A, int par, int m, int tid,
                                            float* Xl, float* Tg, const float* W4,
                                            const float* zs, v4f a0, v4f a1){
  stage256(zs, 512, 0,   Xl, tid); gemmK256(W4,        Xl, tid, a0, a1);
  stage256(zs, 512, 256, Xl, tid); gemmK256(W4 + 4096, Xl, tid, a0, a1);
  int q = tid & 7, b = tid >> 3;
  __syncthreads();
  Tg[b*16 + q]     = hsum(a0);
  Tg[b*16 + q + 8] = hsum(a1);
  __syncthreads();
  if (tid < 128){
    int b2 = tid >> 2, ul = tid & 3;
    int u = m*4 + ul;
    float gi = Tg[b2*16 + ul*4 + 0];
    float gf = Tg[b2*16 + ul*4 + 1];
    float gg = Tg[b2*16 + ul*4 + 2];
    float go = Tg[b2*16 + ul*4 + 3];
    v4f bs = *(const v4f*)&A.biasP1[u*4];
    gi += bs.x; gf += bs.y; gg += bs.z; go += bs.w;
    float co = A.c1g[b2*512 + u];                                // block-local
    float zo = cld(&A.z1[(par^1)*16384 + b2*512 + u]);           // sc1
    float c2 = sigf(gf)*co + sigf(gi)*tanhf(gg);
    float h  = sigf(go)*tanhf(c2);
    A.c1g[b2*512 + u] = 0.1f*co + 0.9f*c2;
    cst(&A.z1[par*16384 + b2*512 + u], 0.1f*zo + 0.9f*h);        // cross-block (sc1)
  }
}

// ---- gpre0 + dec prefetch for next step. z0 from rotating slot (cached) ----
__device__ __forceinline__ void gpre0_body(const Args& A, int blk, int tid,
                                           float* Xl, const float* W4, const float* Wd,
                                           const float* zs){
  v4f a0={0,0,0,0}, a1={0,0,0,0};
  v4f dd4={0,0,0,0};
  int q = tid & 7, b = tid >> 3;
  stage256(zs, 512, 0, Xl, tid);
  gemmK256(W4, Xl, tid, a0, a1);
  if (blk < 32){
    #pragma unroll 8
    for (int i = 0; i < 32; ++i){
      int kl = q*32 + i;
      dd4 += Xl[b*260 + kl] * (*(const v4f*)&Wd[kl*4]);
    }
  }
  stage256(zs, 512, 256, Xl, tid);
  gemmK256(W4 + 4096, Xl, tid, a0, a1);
  if (blk < 32){
    #pragma unroll 8
    for (int i = 0; i < 32; ++i){
      int kl = q*32 + i;
      dd4 += Xl[b*260 + kl] * (*(const v4f*)&Wd[(256+kl)*4]);
    }
    #pragma unroll
    for (int m = 1; m < 8; m <<= 1){
      dd4.x += __shfl_xor(dd4.x, m); dd4.y += __shfl_xor(dd4.y, m);
      dd4.z += __shfl_xor(dd4.z, m); dd4.w += __shfl_xor(dd4.w, m);
    }
    if (q == 0){
      float* dp = &A.dec[b*128 + blk*4];                         // cross-block (sc1)
      cst(&dp[0], dd4.x); cst(&dp[1], dd4.y);
      cst(&dp[2], dd4.z); cst(&dp[3], dd4.w);
    }
  }
  float* dst = A.gpre0 + b*2048 + blk*16;                        // block-local
  dst[q]     = hsum(a0);
  dst[q + 8] = hsum(a1);
}

// ---- grid barrier: fence-free, TREE RELEASE.
// Arrival: per-block flag (256 distinct addresses). Release: collector posts 8
// go-flags on separate 128B-spaced lines; each block spins on go[blk&7] ->
// <=32 spinners per line (vs 255 on one line), spread across MALL slices. ----
#define COLL 255
__device__ __forceinline__ void gsync(unsigned* bars, unsigned idx){
  unsigned* go = bars + 384;   // go line g at bars[384 + g*32]
  asm volatile("" ::: "memory");
  __syncthreads();
  if (threadIdx.x == 0)
    __hip_atomic_store(&bars[blockIdx.x], idx, __ATOMIC_RELAXED, __HIP_MEMORY_SCOPE_AGENT);
  if (blockIdx.x == COLL){
    while (__hip_atomic_load(&bars[threadIdx.x], __ATOMIC_RELAXED, __HIP_MEMORY_SCOPE_AGENT) < idx)
      __builtin_amdgcn_s_sleep(1);
    __syncthreads();
    if (threadIdx.x < 8)
      __hip_atomic_store(&go[threadIdx.x*32], idx, __ATOMIC_RELAXED, __HIP_MEMORY_SCOPE_AGENT);
  }
  if (threadIdx.x == 0){
    unsigned* myg = &go[(blockIdx.x & 7)*32];
    while (__hip_atomic_load(myg, __ATOMIC_RELAXED, __HIP_MEMORY_SCOPE_AGENT) < idx)
      __builtin_amdgcn_s_sleep(1);
  }
  __syncthreads();
  asm volatile("" ::: "memory");
}

// ---------------- persistent loop (grid=256, 1 block/CU by LDS) ----------------
// roles: blk 0-31: att (A) + L0 (B) + gpre0/dec (C)
//        blk 32-127: L0 (B) + gpre0 (C)
//        blk 128-191: gpre1(t+1) (A) + LSTM1 (B:z1-half, C:z0-half)
//        blk 192-232: out(t-1) (A) + LSTM1 (B,C)
//        blk 233-255: LSTM1 (B,C)
__global__ void __launch_bounds__(256, 1) k_loop(Args A){
  extern __shared__ float L[];
  float* Xl = L + L_XL;
  float* Tg = L + L_TG;
  float* W4 = L + L_W4;
  float* WX = L + L_WX;
  int blk = blockIdx.x, tid = threadIdx.x;

  // ---- one-time LDS weight residency ----
  if (blk < 128){
    const float* src = A.W0pack + (size_t)blk*16384;
    for (int i = tid*4; i < 16384; i += 1024) *(v4f*)&W4[i] = *(const v4f*)&src[i];
    if (blk < 32){
      const float* sd = A.Wdpack + (size_t)blk*2048;
      for (int i = tid; i < 2048; i += 256) WX[i] = sd[i];
      for (int i = tid; i < 3968; i += 256) L[L_GS + i] = A.G[i];
    }
  } else {
    const float* src = A.W1pack + (size_t)(blk-128)*16384;
    for (int i = tid*4; i < 16384; i += 1024) *(v4f*)&W4[i] = *(const v4f*)&src[i];
    if (blk < 192){
      const float* sp = A.Wp1pack + (size_t)(blk-128)*8192;
      for (int i = tid*4; i < 8192; i += 1024) *(v4f*)&WX[i] = *(const v4f*)&sp[i];
    } else if (blk < 233){
      const float* sf = A.WFpack + (size_t)(blk-192)*2048;
      for (int i = tid; i < 2048; i += 256) WX[i] = sf[i];
    }
  }
  __syncthreads();

  unsigned sidx = 0;
  v4f l1a0, l1a1;    // lstm1 accumulators, live across the B->C barrier

  // bootstrap gpre1(0) (parity 0)
  if (blk >= 128 && blk < 192) gp1_body(A, 0, blk-128, tid, Xl, WX);
  gsync(A.bars, ++sidx);

  for (int t = 0; t < LSEQ; ++t){
    int par = t & 1;
    const float* zsR = zslot(A, t);       // z0(t-1)
    float*       zsW = zslot(A, t+1);     // z0(t)
    // ---- phase A: attention | gpre1(t+1) | out(t-1) ----
    if (blk < 32){
      att_body(A, t, blk, tid, L);
    } else if (blk >= 128 && blk < 192){
      if (t < 255) gp1_body(A, t+1, blk-128, tid, Xl, WX);
    } else if (blk >= 192 && blk < 233){
      if (t > 0) out_phase(A, A.z1 + (par^1)*16384, A.att_c + (par^1)*16384,
                           t-1, blk-192, tid, Xl, Tg, WX);
    }
    gsync(A.bars, ++sidx);
    // ---- phase B: L0 gates (blk<128) | LSTM1 z1-half (blk>=128) ----
    if (blk < 128){
      l0_body(A, par, blk, tid, Xl, Tg, W4, zsR, zsW);
    } else {
      const float* z1rd = A.z1 + (par^1)*16384;
      l1a0 = (v4f){0,0,0,0}; l1a1 = (v4f){0,0,0,0};
      stage256c(z1rd, 512, 0,   Xl, tid); gemmK256(W4 + 8192,  Xl, tid, l1a0, l1a1);
      stage256c(z1rd, 512, 256, Xl, tid); gemmK256(W4 + 12288, Xl, tid, l1a0, l1a1);
    }
    gsync(A.bars, ++sidx);
    // ---- phase C: LSTM1 z0-half+epilogue | gpre0/dec prefetch ----
    if (blk >= 128) lstm1_partC(A, par, blk-128, tid, Xl, Tg, W4, zsW, l1a0, l1a1);
    else if (t < 255) gpre0_body(A, blk, tid, Xl, W4 + 8192, WX, zsW);
    gsync(A.bars, ++sidx);
  }
  // ---- tail: out(255) (parity 1) ----
  if (blk >= 192 && blk < 233)
    out_phase(A, A.z1 + 16384, A.att_c + 16384, 255, blk-192, tid, Xl, Tg, WX);
}

// ---------------- postnet conv (kernel=5, pad=2) as tiled GEMM ----------------
__global__ void __launch_bounds__(256) k_conv(const float* __restrict__ in,
                       const float* __restrict__ Wt,
                       const float* __restrict__ sc, const float* __restrict__ sh,
                       float* __restrict__ out0, const float* __restrict__ before,
                       float* __restrict__ after, int C, int N, int mode)
{
  __shared__ __align__(16) float As[16][64];
  __shared__ __align__(16) float Bs[16][64];
  int bx = blockIdx.x;
  int b = bx >> 2, l0 = (bx & 3)*64;
  int n0 = blockIdx.y*64;
  int tid = threadIdx.x, tx = tid & 15, ty = tid >> 4;
  float acc[4][4];
  #pragma unroll
  for (int i = 0; i < 4; ++i)
    #pragma unroll
    for (int j = 0; j < 4; ++j) acc[i][j] = 0.f;
  for (int k = 0; k < 5; ++k){
    int shift = k - 2;
    for (int c0 = 0; c0 < C; c0 += 16){
      #pragma unroll
      for (int i = 0; i < 4; ++i){
        int e = tid + i*256; int cc = e >> 6, ll = e & 63;
        int l = l0 + ll + shift;
        As[cc][ll] = ((unsigned)l < 256u) ? in[((size_t)(b*C + c0+cc))*256 + l] : 0.f;
        int n = n0 + ll;
        Bs[cc][ll] = (n < N) ? Wt[((size_t)k*C + c0+cc)*(size_t)N + n] : 0.f;
      }
      __syncthreads();
      #pragma unroll
      for (int cc = 0; cc < 16; ++cc){
        const float4 av = *reinterpret_cast<const float4*>(&As[cc][ty<<2]);
        const float4 bv = *reinterpret_cast<const float4*>(&Bs[cc][tx<<2]);
        acc[0][0]+=av.x*bv.x; acc[0][1]+=av.x*bv.y; acc[0][2]+=av.x*bv.z; acc[0][3]+=av.x*bv.w;
        acc[1][0]+=av.y*bv.x; acc[1][1]+=av.y*bv.y; acc[1][2]+=av.y*bv.z; acc[1][3]+=av.y*bv.w;
        acc[2][0]+=av.z*bv.x; acc[2][1]+=av.z*bv.y; acc[2][2]+=av.z*bv.z; acc[2][3]+=av.z*bv.w;
        acc[3][0]+=av.w*bv.x; acc[3][1]+=av.w*bv.y; acc[3][2]+=av.w*bv.z; acc[3][3]+=av.w*bv.w;
      }
      __syncthreads();
    }
  }
  #pragma unroll
  for (int i = 0; i < 4; ++i){
    int l = l0 + (ty<<2) + i;
    #pragma unroll
    for (int j = 0; j < 4; ++j){
      int n = n0 + (tx<<2) + j;
      if (n < N){
        float v = sc[n]*acc[i][j] + sh[n];
        if (mode == 0){
          out0[((size_t)(b*N + n))*256 + l] = tanhf(v);
        } else {
          size_t ob2 = ((size_t)b*256 + l)*80 + n;
          after[ob2] = before[ob2] + v;
        }
      }
    }
  }
}

extern "C" void kernel_launch(void* const* d_in, const int* in_sizes, int n_in,
                              void* d_out, int out_size, void* d_ws, size_t ws_size,
                              hipStream_t stream) {
  Args A;
  A.enc_z = (const float*)d_in[0];  A.ys = (const float*)d_in[1];
  A.ilens = (const int*)d_in[3];
  A.W_enc = (const float*)d_in[4];  A.b_enc = (const float*)d_in[5];
  A.W_dec = (const float*)d_in[6];  A.loc_kernel = (const float*)d_in[7];
  A.W_att = (const float*)d_in[8];  A.g_w = (const float*)d_in[9];  A.g_b = (const float*)d_in[10];
  A.Wp0 = (const float*)d_in[11];   A.bp0 = (const float*)d_in[12];
  A.Wp1 = (const float*)d_in[13];   A.bp1 = (const float*)d_in[14];
  A.Wih0 = (const float*)d_in[15];  A.Whh0 = (const float*)d_in[16];
  A.bih0 = (const float*)d_in[17];  A.bhh0 = (const float*)d_in[18];
  A.Wih1 = (const float*)d_in[19];  A.Whh1 = (const float*)d_in[20];
  A.bih1 = (const float*)d_in[21];  A.bhh1 = (const float*)d_in[22];
  A.Wf = (const float*)d_in[23];    A.bf = (const float*)d_in[24];
  A.Wq = (const float*)d_in[25];    A.bq = (const float*)d_in[26];
  A.pk0 = (const float*)d_in[27];   A.pb0 = (const float*)d_in[28];
  A.bg0 = (const float*)d_in[29];   A.bb0 = (const float*)d_in[30];
  A.pk1 = (const float*)d_in[31];   A.pb1 = (const float*)d_in[32];
  A.bg1 = (const float*)d_in[33];   A.bb1 = (const float*)d_in[34];
  A.pk2 = (const float*)d_in[35];   A.pb2 = (const float*)d_in[36];
  A.bg2 = (const float*)d_in[37];   A.bb2 = (const float*)d_in[38];

  float* ws = (float*)d_ws;
  size_t off = 0;
  auto alloc = [&](size_t n){ float* p = ws + off; off += n; return p; };
  A.enc_proj   = alloc(1048576);
  A.pre_tmp    = alloc(2097152);
  A.pre_all    = alloc(2097152);
  A.G          = alloc(3968);
  A.dec        = alloc(4096);
  A.att_c      = alloc(32768);
  A.z0         = alloc(16384);
  A.z1         = alloc(32768);
  A.c0g        = alloc(16384);
  A.c1g        = alloc(16384);
  A.gpre0      = alloc(65536);
  A.gpre1      = alloc(131072);
  A.biasP0     = alloc(2048);
  A.biasP1     = alloc(2048);
  A.before_t   = alloc(655360);
  A.h0         = alloc(4194304);
  A.h1         = alloc(4194304);
  A.Wt0        = alloc(204800);
  A.Wt1        = alloc(1310720);
  A.Wt2        = alloc(204800);
  A.s0 = alloc(512); A.t0s = alloc(512);
  A.s1 = alloc(512); A.t1s = alloc(512);
  A.s2 = alloc(128); A.t2s = alloc(128);
  A.bars = (unsigned*)alloc(1024);
  // weight packs alias the postnet activation buffers (consumed by k_loop
  // before postnet runs; k_init refills them at the start of every replay)
  A.W0pack  = A.h0;                       // 128*16384 = 2097152
  A.W1pack  = A.h0 + 2097152;             // 2097152
  A.Wp1pack = A.h1;                       // 64*8192 = 524288
  A.WFpack  = A.h1 + 524288;              // 41*2048 = 83968
  A.Wdpack  = A.h1 + 524288 + 83968;      // 32*2048 = 65536 (packs end 673792)
  // rotating z0 slots: 257 x 16384 floats, never-reused addresses.
  //   slots 0..213  -> h1 tail  [673792 .. 4179968) < 4194304
  //   slots 214..256 -> pre_tmp [0 .. 704512) (dead after k_pre1)
  // conv-2 overwrites h1 only after k_loop retires.
  A.z0rA = A.h1 + 673792;
  A.z0rB = A.pre_tmp;

  float* out = (float*)d_out;
  A.out_after  = out;
  A.out_before = out + 655360;
  A.out_logits = out + 1310720;
  A.out_aws    = out + 1318912;

  hipFuncSetAttribute((const void*)k_loop,
                      hipFuncAttributeMaxDynamicSharedMemorySize, DYN_L);

  k_init<<<dim3(1024), dim3(256), 0, stream>>>(A);
  k_encproj<<<dim3(256), dim3(256), 0, stream>>>(A);
  k_pre0<<<dim3(256), dim3(256), 0, stream>>>(A);
  k_pre1<<<dim3(256), dim3(256), 0, stream>>>(A);

  // Plain launch: grid=256 with 130.6 KiB dynamic LDS forces 1 block/CU on
  // 256 CUs -> all blocks co-resident, so the flag-array grid barrier is safe.
  k_loop<<<dim3(256), dim3(256), DYN_L, stream>>>(A);

  k_conv<<<dim3(128,8), dim3(256), 0, stream>>>(A.before_t, A.Wt0, A.s0, A.t0s, A.h0, nullptr, nullptr, 80, 512, 0);
  k_conv<<<dim3(128,8), dim3(256), 0, stream>>>(A.h0, A.Wt1, A.s1, A.t1s, A.h1, nullptr, nullptr, 512, 512, 0);
  k_conv<<<dim3(128,2), dim3(256), 0, stream>>>(A.h1, A.Wt2, A.s2, A.t2s, nullptr, A.out_before, A.out_after, 512, 80, 1);
}